// Round 6
// baseline (2967.085 us; speedup 1.0000x reference)
//
#include <hip/hip_runtime.h>
#include <math.h>

// MultiViewAggregation — round 6.
// A: PBR MLP, named-register activations + LDS-staged weights (uniform ds_read
//    broadcast, conflict-free). fb reduction buffer aliases dead w2/w3 region.
// B: per-pixel transformer, 4 px per 512-thread block; unit=(c4,row-pair) with
//    2 independent acc chains (16 FMA per 2 weight loads).

#define NPIX 16384

__device__ __forceinline__ float elu_f(float x){ return x > 0.f ? x : (__expf(x) - 1.f); }
__device__ __forceinline__ float gelu_f(float x){ return 0.5f*x*(1.f + erff(x*0.70710678118654752f)); }

// ===================== Kernel A =====================
#define NTA 384
#define NBA (NPIX/4)

// LDS float offsets (weights staged; fb aliases [0..6336) = w2+w3 region)
// LW2=0(4096) LW3=4096(4096) LW1=8192(448) LW4=8640(2048)
// LB1=10688 LB2=10752 LB3=10816 LB4=10880 LLG=10912 LLB=10919 -> 10926

#define FMA4(A, S, WV) { float4 _w = (WV); \
  A.x = fmaf((S), _w.x, A.x); A.y = fmaf((S), _w.y, A.y); \
  A.z = fmaf((S), _w.z, A.z); A.w = fmaf((S), _w.w, A.w); }

#define ELU4(A) make_float4(elu_f(A.x), elu_f(A.y), elu_f(A.z), elu_f(A.w))

#define AK4W(A, Sq, W, base, LD) \
  FMA4(A, (Sq).x, W[(base)]) \
  FMA4(A, (Sq).y, W[(base)+(LD)]) \
  FMA4(A, (Sq).z, W[(base)+2*(LD)]) \
  FMA4(A, (Sq).w, W[(base)+3*(LD)])

#define COL64(A, W, B4, cb, S) { A = B4[cb]; \
  AK4W(A, S##0,  W,  0*64+(cb), 16) AK4W(A, S##1,  W,  1*64+(cb), 16) \
  AK4W(A, S##2,  W,  2*64+(cb), 16) AK4W(A, S##3,  W,  3*64+(cb), 16) \
  AK4W(A, S##4,  W,  4*64+(cb), 16) AK4W(A, S##5,  W,  5*64+(cb), 16) \
  AK4W(A, S##6,  W,  6*64+(cb), 16) AK4W(A, S##7,  W,  7*64+(cb), 16) \
  AK4W(A, S##8,  W,  8*64+(cb), 16) AK4W(A, S##9,  W,  9*64+(cb), 16) \
  AK4W(A, S##10, W, 10*64+(cb), 16) AK4W(A, S##11, W, 11*64+(cb), 16) \
  AK4W(A, S##12, W, 12*64+(cb), 16) AK4W(A, S##13, W, 13*64+(cb), 16) \
  AK4W(A, S##14, W, 14*64+(cb), 16) AK4W(A, S##15, W, 15*64+(cb), 16) }

#define LAYER64(D, S, W, B4) { float4 _a; \
  COL64(_a, W, B4, 0,  S) D##0  = ELU4(_a); \
  COL64(_a, W, B4, 1,  S) D##1  = ELU4(_a); \
  COL64(_a, W, B4, 2,  S) D##2  = ELU4(_a); \
  COL64(_a, W, B4, 3,  S) D##3  = ELU4(_a); \
  COL64(_a, W, B4, 4,  S) D##4  = ELU4(_a); \
  COL64(_a, W, B4, 5,  S) D##5  = ELU4(_a); \
  COL64(_a, W, B4, 6,  S) D##6  = ELU4(_a); \
  COL64(_a, W, B4, 7,  S) D##7  = ELU4(_a); \
  COL64(_a, W, B4, 8,  S) D##8  = ELU4(_a); \
  COL64(_a, W, B4, 9,  S) D##9  = ELU4(_a); \
  COL64(_a, W, B4, 10, S) D##10 = ELU4(_a); \
  COL64(_a, W, B4, 11, S) D##11 = ELU4(_a); \
  COL64(_a, W, B4, 12, S) D##12 = ELU4(_a); \
  COL64(_a, W, B4, 13, S) D##13 = ELU4(_a); \
  COL64(_a, W, B4, 14, S) D##14 = ELU4(_a); \
  COL64(_a, W, B4, 15, S) D##15 = ELU4(_a); }

#define COL32(A, W, B4, cb, S) { A = B4[cb]; \
  AK4W(A, S##0,  W,  0*32+(cb), 8) AK4W(A, S##1,  W,  1*32+(cb), 8) \
  AK4W(A, S##2,  W,  2*32+(cb), 8) AK4W(A, S##3,  W,  3*32+(cb), 8) \
  AK4W(A, S##4,  W,  4*32+(cb), 8) AK4W(A, S##5,  W,  5*32+(cb), 8) \
  AK4W(A, S##6,  W,  6*32+(cb), 8) AK4W(A, S##7,  W,  7*32+(cb), 8) \
  AK4W(A, S##8,  W,  8*32+(cb), 8) AK4W(A, S##9,  W,  9*32+(cb), 8) \
  AK4W(A, S##10, W, 10*32+(cb), 8) AK4W(A, S##11, W, 11*32+(cb), 8) \
  AK4W(A, S##12, W, 12*32+(cb), 8) AK4W(A, S##13, W, 13*32+(cb), 8) \
  AK4W(A, S##14, W, 14*32+(cb), 8) AK4W(A, S##15, W, 15*32+(cb), 8) }

#define COLL1(A, B4, cb) { A = B4[cb]; \
  FMA4(A, xl0, W1v[ 0+(cb)]) FMA4(A, xl1, W1v[16+(cb)]) \
  FMA4(A, xl2, W1v[32+(cb)]) FMA4(A, xl3, W1v[48+(cb)]) \
  FMA4(A, xl4, W1v[64+(cb)]) FMA4(A, xl5, W1v[80+(cb)]) \
  FMA4(A, xl6, W1v[96+(cb)]) }

#define SHF32(A) { A.x += __shfl_xor(A.x, 32); A.y += __shfl_xor(A.y, 32); \
                   A.z += __shfl_xor(A.z, 32); A.w += __shfl_xor(A.w, 32); }

#define ST4(p, o, A) { (p)[(o)] = A.x; (p)[(o)+1] = A.y; (p)[(o)+2] = A.z; (p)[(o)+3] = A.w; }

__global__ __launch_bounds__(NTA)
void mva_phaseA(const float* __restrict__ view_dir, const float* __restrict__ normal,
                const float* __restrict__ DL,
                const float* __restrict__ ln_g, const float* __restrict__ ln_b,
                const float* __restrict__ w1, const float* __restrict__ b1,
                const float* __restrict__ w2, const float* __restrict__ b2,
                const float* __restrict__ w3, const float* __restrict__ b3,
                const float* __restrict__ w4, const float* __restrict__ b4,
                float* __restrict__ feat)
{
  __shared__ __align__(16) float Wl[10928];
  const int t   = threadIdx.x;
  const int pxv = t & 31;
  const int sg  = t >> 5;
  const int px  = blockIdx.x*4 + (pxv >> 3);
  const int view = pxv & 7;

  // ---- stage weights into LDS ----
  {
    float4* d = (float4*)Wl;
    const float4* s2 = (const float4*)w2;
    for (int i = t; i < 1024; i += NTA) d[i] = s2[i];
    const float4* s3 = (const float4*)w3;
    for (int i = t; i < 1024; i += NTA) d[1024+i] = s3[i];
    const float4* s1 = (const float4*)w1;
    for (int i = t; i < 112;  i += NTA) d[2048+i] = s1[i];
    const float4* s4 = (const float4*)w4;
    for (int i = t; i < 512;  i += NTA) d[2160+i] = s4[i];
    if (t < 16)      ((float4*)(Wl+10688))[t]    = ((const float4*)b1)[t];
    else if (t < 32) ((float4*)(Wl+10752))[t-16] = ((const float4*)b2)[t-16];
    else if (t < 48) ((float4*)(Wl+10816))[t-32] = ((const float4*)b3)[t-32];
    else if (t < 56) ((float4*)(Wl+10880))[t-48] = ((const float4*)b4)[t-48];
    else if (t < 63) Wl[10912 + t-56] = ln_g[t-56];
    else if (t < 70) Wl[10919 + t-63] = ln_b[t-63];
  }

  // ---- inputs + 7-wide LN (overlaps staging latency) ----
  const float nm0 = normal[px*3+0], nm1 = normal[px*3+1], nm2 = normal[px*3+2];
  const float* vd = view_dir + (px*8 + view)*3;
  const float vd0 = vd[0], vd1 = vd[1], vd2 = vd[2];
  const float* dl = DL + px*84 + sg*7;
  const float d0=dl[0], d1=dl[1], d2=dl[2], d3=dl[3], d4=dl[4], d5=dl[5], d6=dl[6];

  const float DLdotN = d0*nm0 + d1*nm1 + d2*nm2;
  const float hv     = (d0*vd0 + d1*vd1 + d2*vd2 + 1.f)*0.5f;
  const float fres   = exp2f((-5.55472f*hv - 6.98316f)*hv);
  const float VdotN  = vd0*nm0 + vd1*nm1 + vd2*nm2;

  const float x0 = DLdotN, x1 = d3, x2 = d4, x3 = d5, x4 = d6, x5 = fres, x6 = VdotN;
  const float m  = (x0+x1+x2+x3+x4+x5+x6)*(1.f/7.f);
  float q, var = 0.f;
  q = x0-m; var += q*q; q = x1-m; var += q*q; q = x2-m; var += q*q;
  q = x3-m; var += q*q; q = x4-m; var += q*q; q = x5-m; var += q*q;
  q = x6-m; var += q*q;
  const float rs = rsqrtf(var*(1.f/7.f) + 1e-5f);

  __syncthreads();   // weights staged

  const float xl0 = (x0-m)*rs*Wl[10912+0] + Wl[10919+0];
  const float xl1 = (x1-m)*rs*Wl[10912+1] + Wl[10919+1];
  const float xl2 = (x2-m)*rs*Wl[10912+2] + Wl[10919+2];
  const float xl3 = (x3-m)*rs*Wl[10912+3] + Wl[10919+3];
  const float xl4 = (x4-m)*rs*Wl[10912+4] + Wl[10919+4];
  const float xl5 = (x5-m)*rs*Wl[10912+5] + Wl[10919+5];
  const float xl6 = (x6-m)*rs*Wl[10912+6] + Wl[10919+6];

  const float4* W1v = (const float4*)(Wl + 8192);
  const float4* B1v = (const float4*)(Wl + 10688);
  const float4* W2v = (const float4*)(Wl + 0);
  const float4* B2v = (const float4*)(Wl + 10752);
  const float4* W3v = (const float4*)(Wl + 4096);
  const float4* B3v = (const float4*)(Wl + 10816);
  const float4* W4v = (const float4*)(Wl + 8640);
  const float4* B4v = (const float4*)(Wl + 10880);

  float4 Y0,Y1,Y2,Y3,Y4,Y5,Y6,Y7,Y8,Y9,Y10,Y11,Y12,Y13,Y14,Y15;
  { float4 _a;
    COLL1(_a, B1v, 0)  Y0  = ELU4(_a);
    COLL1(_a, B1v, 1)  Y1  = ELU4(_a);
    COLL1(_a, B1v, 2)  Y2  = ELU4(_a);
    COLL1(_a, B1v, 3)  Y3  = ELU4(_a);
    COLL1(_a, B1v, 4)  Y4  = ELU4(_a);
    COLL1(_a, B1v, 5)  Y5  = ELU4(_a);
    COLL1(_a, B1v, 6)  Y6  = ELU4(_a);
    COLL1(_a, B1v, 7)  Y7  = ELU4(_a);
    COLL1(_a, B1v, 8)  Y8  = ELU4(_a);
    COLL1(_a, B1v, 9)  Y9  = ELU4(_a);
    COLL1(_a, B1v, 10) Y10 = ELU4(_a);
    COLL1(_a, B1v, 11) Y11 = ELU4(_a);
    COLL1(_a, B1v, 12) Y12 = ELU4(_a);
    COLL1(_a, B1v, 13) Y13 = ELU4(_a);
    COLL1(_a, B1v, 14) Y14 = ELU4(_a);
    COLL1(_a, B1v, 15) Y15 = ELU4(_a);
  }

  float4 Z0,Z1,Z2,Z3,Z4,Z5,Z6,Z7,Z8,Z9,Z10,Z11,Z12,Z13,Z14,Z15;
  LAYER64(Z, Y, W2v, B2v)
  LAYER64(Y, Z, W3v, B3v)

  float4 F0,F1,F2,F3,F4,F5,F6,F7;
  { float4 _a;
    COL32(_a, W4v, B4v, 0, Y) F0 = _a;
    COL32(_a, W4v, B4v, 1, Y) F1 = _a;
    COL32(_a, W4v, B4v, 2, Y) F2 = _a;
    COL32(_a, W4v, B4v, 3, Y) F3 = _a;
    COL32(_a, W4v, B4v, 4, Y) F4 = _a;
    COL32(_a, W4v, B4v, 5, Y) F5 = _a;
    COL32(_a, W4v, B4v, 6, Y) F6 = _a;
    COL32(_a, W4v, B4v, 7, Y) F7 = _a;
  }

  SHF32(F0) SHF32(F1) SHF32(F2) SHF32(F3)
  SHF32(F4) SHF32(F5) SHF32(F6) SHF32(F7)

  __syncthreads();   // all waves past layer3/4 -> w2/w3 region reusable as fb
  if ((t & 63) < 32){
    float* row = Wl + (t>>6)*1056 + pxv*33;   // fb[6][32][33] in [0..6336)
    ST4(row, 0,  F0) ST4(row, 4,  F1) ST4(row, 8,  F2) ST4(row, 12, F3)
    ST4(row, 16, F4) ST4(row, 20, F5) ST4(row, 24, F6) ST4(row, 28, F7)
  }
  __syncthreads();

  for (int u = t; u < 1024; u += NTA){
    const int pv = u >> 5, c = u & 31;
    float s = 0.f;
    #pragma unroll
    for (int w = 0; w < 6; ++w) s += Wl[w*1056 + pv*33 + c];
    feat[(size_t)blockIdx.x*1024 + u] = s;
  }
}

// ===================== Kernel B =====================
#define NTB 512
#define NBB (NPIX/4)

constexpr int BXIN  = 0;      // [32][100]
constexpr int BXCUR = 3200;   // [32][100]
constexpr int BXLN  = 6400;   // [32][100]
constexpr int BHID  = 9600;   // [32][132] (chunks) / [4][260] (per-px)
constexpr int BVB   = 13824;  // [32][36]
constexpr int BMEAN = 14976;  // [4][32]
constexpr int BVAR  = 15104;  // [4][32]
constexpr int BWGT  = 15232;  // 32
constexpr int BXS   = 15264;  // [4][96]
constexpr int BXSLN = 15648;  // [4][96]
constexpr int BTOT  = 16032;  // 64128 B -> 2 blocks/CU

__device__ __forceinline__ void fma4(float4& a, float s, const float4 w){
  a.x = fmaf(s, w.x, a.x); a.y = fmaf(s, w.y, a.y);
  a.z = fmaf(s, w.z, a.z); a.w = fmaf(s, w.w, a.w);
}

// LN of 32 rows x 96 (t<256, 8 lanes/row), bank-staggered cols, stride 100.
__device__ __forceinline__ void ln32(const float* __restrict__ in,
                                     float* __restrict__ out,
                                     const float* __restrict__ g, const float* __restrict__ b,
                                     int t)
{
  if (t < 256){
    const int r = t >> 3, l8 = t & 7;
    const float* row = in + r*100;
    float vals[12]; int cols[12];
    float s1 = 0.f, s2 = 0.f;
    #pragma unroll
    for (int i = 0; i < 12; ++i){
      int c = l8 + 8*i + 8*(r & 7); if (c >= 96) c -= 96;
      float a = row[c];
      cols[i] = c; vals[i] = a; s1 += a; s2 += a*a;
    }
    s1 += __shfl_xor(s1, 1); s2 += __shfl_xor(s2, 1);
    s1 += __shfl_xor(s1, 2); s2 += __shfl_xor(s2, 2);
    s1 += __shfl_xor(s1, 4); s2 += __shfl_xor(s2, 4);
    float mean = s1*(1.f/96.f);
    float var  = s2*(1.f/96.f) - mean*mean;
    float rsd = rsqrtf(var + 1e-5f);
    float* orow = out + r*100;
    #pragma unroll
    for (int i = 0; i < 12; ++i){
      int c = cols[i];
      orow[c] = (vals[i]-mean)*rsd*g[c] + b[c];
    }
  }
}

// LN of 4 rows x 96 (t<64, 16 lanes/row), stride 96.
__device__ __forceinline__ void lnP(const float* __restrict__ in,
                                    float* __restrict__ out,
                                    const float* __restrict__ g, const float* __restrict__ b,
                                    int t)
{
  if (t < 64){
    const int r = t >> 4, l = t & 15;
    const float* row = in + r*96;
    float vals[6];
    float s1 = 0.f, s2 = 0.f;
    #pragma unroll
    for (int i = 0; i < 6; ++i){
      float a = row[l + 16*i];
      vals[i] = a; s1 += a; s2 += a*a;
    }
    s1 += __shfl_xor(s1, 1); s2 += __shfl_xor(s2, 1);
    s1 += __shfl_xor(s1, 2); s2 += __shfl_xor(s2, 2);
    s1 += __shfl_xor(s1, 4); s2 += __shfl_xor(s2, 4);
    s1 += __shfl_xor(s1, 8); s2 += __shfl_xor(s2, 8);
    float mean = s1*(1.f/96.f);
    float var  = s2*(1.f/96.f) - mean*mean;
    float rsd = rsqrtf(var + 1e-5f);
    float* orow = out + r*96;
    #pragma unroll
    for (int i = 0; i < 6; ++i){
      int c = l + 16*i;
      orow[c] = (vals[i]-mean)*rsd*g[c] + b[c];
    }
  }
}

// 32-row matmul: unit=(c4, row-pair). 2 independent acc chains, 16 FMA / 2 W-loads.
template<int K, int C, int LDW, bool GELU, bool HASB, bool RES, bool ACC>
__device__ __forceinline__ void mmR32(const float* __restrict__ inb, int S,
                                      const float* __restrict__ Wg, const float* __restrict__ bg,
                                      float* __restrict__ outb, int So,
                                      const float* __restrict__ residb, int Sr, int t)
{
  constexpr int C4 = C/4;
  const float4* __restrict__ W4 = (const float4*)Wg;
  for (int gi = t; gi < C4*16; gi += NTB){
    const int rp = gi & 15, c4 = gi >> 4;
    const float2* x0 = (const float2*)(inb + (2*rp)*S);
    const float2* x1 = (const float2*)(inb + (2*rp+1)*S);
    float4 a0 = HASB ? ((const float4*)bg)[c4] : make_float4(0.f,0.f,0.f,0.f);
    float4 a1 = a0;
    #pragma unroll 8
    for (int k2 = 0; k2 < K/2; ++k2){
      float2 xa = x0[k2], xb = x1[k2];
      float4 wA = W4[(2*k2)*(LDW/4) + c4];
      float4 wB = W4[(2*k2+1)*(LDW/4) + c4];
      fma4(a0, xa.x, wA); fma4(a0, xa.y, wB);
      fma4(a1, xb.x, wA); fma4(a1, xb.y, wB);
    }
    if (GELU){
      a0.x=gelu_f(a0.x); a0.y=gelu_f(a0.y); a0.z=gelu_f(a0.z); a0.w=gelu_f(a0.w);
      a1.x=gelu_f(a1.x); a1.y=gelu_f(a1.y); a1.z=gelu_f(a1.z); a1.w=gelu_f(a1.w);
    }
    if (RES){
      const float* r0 = residb + (2*rp)*Sr + 4*c4;
      const float* r1 = residb + (2*rp+1)*Sr + 4*c4;
      a0.x += r0[0]; a0.y += r0[1]; a0.z += r0[2]; a0.w += r0[3];
      a1.x += r1[0]; a1.y += r1[1]; a1.z += r1[2]; a1.w += r1[3];
    }
    float* o0 = outb + (2*rp)*So + 4*c4;
    float* o1 = outb + (2*rp+1)*So + 4*c4;
    if (ACC){
      a0.x += o0[0]; a0.y += o0[1]; a0.z += o0[2]; a0.w += o0[3];
      a1.x += o1[0]; a1.y += o1[1]; a1.z += o1[2]; a1.w += o1[3];
    }
    o0[0]=a0.x; o0[1]=a0.y; o0[2]=a0.z; o0[3]=a0.w;
    o1[0]=a1.x; o1[1]=a1.y; o1[2]=a1.z; o1[3]=a1.w;
  }
}

// 4-row (per-pixel) matmul: unit=(c2, kq in [0,8)); k-split 8, shfl-combine.
template<int K, int C, int LDW, bool GELU, bool HASB, bool RES>
__device__ __forceinline__ void mmP4(const float* __restrict__ inb, int S,
                                     const float* __restrict__ Wg, const float* __restrict__ bg,
                                     float* __restrict__ outb, int So,
                                     const float* __restrict__ residb, int Sr, int t)
{
  for (int gi = t; gi < 4*C; gi += NTB){
    const int kq = gi & 7, c2 = gi >> 3;
    const int k0 = kq*(K/8);
    float2 a0 = make_float2(0.f,0.f), a1 = a0, a2 = a0, a3 = a0;
    #pragma unroll 4
    for (int kk = 0; kk < K/8; ++kk){
      const int k = k0 + kk;
      const float2 w = *(const float2*)(Wg + k*LDW + 2*c2);
      const float xA = inb[0*S+k], xB = inb[1*S+k], xC = inb[2*S+k], xD = inb[3*S+k];
      a0.x = fmaf(xA, w.x, a0.x); a0.y = fmaf(xA, w.y, a0.y);
      a1.x = fmaf(xB, w.x, a1.x); a1.y = fmaf(xB, w.y, a1.y);
      a2.x = fmaf(xC, w.x, a2.x); a2.y = fmaf(xC, w.y, a2.y);
      a3.x = fmaf(xD, w.x, a3.x); a3.y = fmaf(xD, w.y, a3.y);
    }
    #pragma unroll
    for (int off = 1; off < 8; off <<= 1){
      a0.x += __shfl_xor(a0.x, off); a0.y += __shfl_xor(a0.y, off);
      a1.x += __shfl_xor(a1.x, off); a1.y += __shfl_xor(a1.y, off);
      a2.x += __shfl_xor(a2.x, off); a2.y += __shfl_xor(a2.y, off);
      a3.x += __shfl_xor(a3.x, off); a3.y += __shfl_xor(a3.y, off);
    }
    if (kq == 0){
      if (HASB){
        const float bx = bg[2*c2], by = bg[2*c2+1];
        a0.x+=bx; a0.y+=by; a1.x+=bx; a1.y+=by;
        a2.x+=bx; a2.y+=by; a3.x+=bx; a3.y+=by;
      }
      if (GELU){
        a0.x=gelu_f(a0.x); a0.y=gelu_f(a0.y); a1.x=gelu_f(a1.x); a1.y=gelu_f(a1.y);
        a2.x=gelu_f(a2.x); a2.y=gelu_f(a2.y); a3.x=gelu_f(a3.x); a3.y=gelu_f(a3.y);
      }
      if (RES){
        a0.x += residb[0*Sr+2*c2]; a0.y += residb[0*Sr+2*c2+1];
        a1.x += residb[1*Sr+2*c2]; a1.y += residb[1*Sr+2*c2+1];
        a2.x += residb[2*Sr+2*c2]; a2.y += residb[2*Sr+2*c2+1];
        a3.x += residb[3*Sr+2*c2]; a3.y += residb[3*Sr+2*c2+1];
      }
      outb[0*So+2*c2] = a0.x; outb[0*So+2*c2+1] = a0.y;
      outb[1*So+2*c2] = a1.x; outb[1*So+2*c2+1] = a1.y;
      outb[2*So+2*c2] = a2.x; outb[2*So+2*c2+1] = a2.y;
      outb[3*So+2*c2] = a3.x; outb[3*So+2*c2+1] = a3.y;
    }
  }
}

__global__ __launch_bounds__(NTB)
void mva_phaseB(const float* __restrict__ rgb, const float* __restrict__ fm,
                const float* __restrict__ proj_err, const float* __restrict__ feat,
                const float* __restrict__ tv1_ln_g, const float* __restrict__ tv1_ln_b,
                const float* __restrict__ tv1_w,
                const float* __restrict__ to1_w, const float* __restrict__ to1_b,
                const float* __restrict__ n1_ln_g, const float* __restrict__ n1_ln_b,
                const float* __restrict__ n1_w1, const float* __restrict__ n1_b1,
                const float* __restrict__ n1_w2, const float* __restrict__ n1_b2,
                const float* __restrict__ tv2_ln_g, const float* __restrict__ tv2_ln_b,
                const float* __restrict__ tv2_w,
                const float* __restrict__ to2_w, const float* __restrict__ to2_b,
                const float* __restrict__ n2_ln_g, const float* __restrict__ n2_ln_b,
                const float* __restrict__ n2_w1, const float* __restrict__ n2_b1,
                const float* __restrict__ n2_w2, const float* __restrict__ n2_b2,
                const float* __restrict__ brdf_ln_g, const float* __restrict__ brdf_ln_b,
                const float* __restrict__ brdf_w1, const float* __restrict__ brdf_b1,
                const float* __restrict__ brdf_w2, const float* __restrict__ brdf_b2,
                float* __restrict__ out)
{
  __shared__ __align__(16) float smem[BTOT];
  const int t = threadIdx.x;
  const int bpx0 = blockIdx.x*4;

  // xin rows r = pl*8+v (32 rows), stride 100
  for (int u = t; u < 2048; u += NTB){
    const int r = u >> 6, k = u & 63;
    const int pl = r >> 3, v = r & 7;
    float val = (k < 3) ? rgb[((bpx0+pl)*8 + v)*3 + k]
                        : fm[(bpx0+pl)*61 + (k-3)];
    smem[BXIN + r*100 + k] = val;
  }
  for (int u = t; u < 1024; u += NTB){
    const int r = u >> 5, c = u & 31;
    smem[BXIN + r*100 + 64 + c] = feat[(size_t)blockIdx.x*1024 + u];
  }
  if (t < 32){
    float pe = proj_err[(bpx0 + (t>>3))*8 + (t&7)];
    float wraw = fmaxf(-log10f(fabsf(pe) + 1e-6f), 0.f);
    float s = wraw;
    s += __shfl_xor(s, 1); s += __shfl_xor(s, 2); s += __shfl_xor(s, 4);
    smem[BWGT + t] = wraw / (s + 1e-6f);
  }
  __syncthreads();

  // tv1
  ln32(smem+BXIN, smem+BXLN, tv1_ln_g, tv1_ln_b, t);
  __syncthreads();
  mmR32<96,32,32,false,false,false,false>(smem+BXLN, 100, tv1_w, nullptr, smem+BVB, 36, nullptr, 0, t);
  __syncthreads();
  if (t < 128){
    const int pl = t >> 5, c = t & 31;
    const float* wn = smem + BWGT + pl*8;
    float m = 0.f;
    #pragma unroll
    for (int v = 0; v < 8; ++v) m += wn[v]*smem[BVB + (pl*8+v)*36 + c];
    float vv = 0.f;
    #pragma unroll
    for (int v = 0; v < 8; ++v){ float d = smem[BVB + (pl*8+v)*36 + c] - m; vv += wn[v]*d*d; }
    smem[BMEAN + pl*32 + c] = m;
    smem[BVAR  + pl*32 + c] = vv;
  }
  __syncthreads();
  for (int u = t; u < 3072; u += NTB){
    const int r = u & 31, c = u >> 5;
    const int pl = r >> 3;
    float val = (c < 32) ? smem[BVB + r*36 + c]
              : (c < 64) ? smem[BMEAN + pl*32 + (c-32)]
                         : smem[BVAR + pl*32 + (c-64)];
    smem[BXLN + r*100 + c] = val;
  }
  __syncthreads();
  mmR32<96,96,96,false,true,true,false>(smem+BXLN, 100, to1_w, to1_b, smem+BXCUR, 100, smem+BXIN, 100, t);
  __syncthreads();

  // n1 (two 128-chunks)
  ln32(smem+BXCUR, smem+BXLN, n1_ln_g, n1_ln_b, t);
  __syncthreads();
  mmR32<96,128,256,true,true,false,false>(smem+BXLN, 100, n1_w1, n1_b1, smem+BHID, 132, nullptr, 0, t);
  __syncthreads();
  mmR32<128,96,96,false,true,true,false>(smem+BHID, 132, n1_w2, n1_b2, smem+BXCUR, 100, smem+BXIN, 100, t);
  __syncthreads();
  mmR32<96,128,256,true,true,false,false>(smem+BXLN, 100, n1_w1 + 128, n1_b1 + 128, smem+BHID, 132, nullptr, 0, t);
  __syncthreads();
  mmR32<128,96,96,false,false,false,true>(smem+BHID, 132, n1_w2 + 128*96, nullptr, smem+BXCUR, 100, nullptr, 0, t);
  __syncthreads();

  // tv2 + stats
  ln32(smem+BXCUR, smem+BXLN, tv2_ln_g, tv2_ln_b, t);
  __syncthreads();
  mmR32<96,32,32,false,false,false,false>(smem+BXLN, 100, tv2_w, nullptr, smem+BVB, 36, nullptr, 0, t);
  __syncthreads();
  if (t < 128){
    const int pl = t >> 5, c = t & 31;
    const float* wn = smem + BWGT + pl*8;
    float m = 0.f;
    #pragma unroll
    for (int v = 0; v < 8; ++v) m += wn[v]*smem[BVB + (pl*8+v)*36 + c];
    float vv = 0.f;
    #pragma unroll
    for (int v = 0; v < 8; ++v){ float d = smem[BVB + (pl*8+v)*36 + c] - m; vv += wn[v]*d*d; }
    smem[BMEAN + pl*32 + c] = m;
    smem[BVAR  + pl*32 + c] = vv;
  }
  __syncthreads();
  // xcat2 per pixel: [v[row0] | mean | var] -> BXSLN
  if (t < 384){
    const int pl = t / 96, k = t - pl*96;
    float val = (k < 32) ? smem[BVB + (pl*8)*36 + k]
              : (k < 64) ? smem[BMEAN + pl*32 + (k-32)]
                         : smem[BVAR + pl*32 + (k-64)];
    smem[BXSLN + pl*96 + k] = val;
  }
  __syncthreads();
  mmP4<96,96,96,false,true,true>(smem+BXSLN, 96, to2_w, to2_b, smem+BXS, 96, smem+BXIN, 800, t);
  __syncthreads();

  // n2
  lnP(smem+BXS, smem+BXSLN, n2_ln_g, n2_ln_b, t);
  __syncthreads();
  mmP4<96,256,256,true,true,false>(smem+BXSLN, 96, n2_w1, n2_b1, smem+BHID, 260, nullptr, 0, t);
  __syncthreads();
  mmP4<256,96,96,false,true,true>(smem+BHID, 260, n2_w2, n2_b2, smem+BXS, 96, smem+BXIN, 800, t);
  __syncthreads();

  // brdf
  lnP(smem+BXS, smem+BXSLN, brdf_ln_g, brdf_ln_b, t);
  __syncthreads();
  mmP4<96,128,128,true,true,false>(smem+BXSLN, 96, brdf_w1, brdf_b1, smem+BHID, 260, nullptr, 0, t);
  __syncthreads();
  mmP4<128,128,128,false,true,false>(smem+BHID, 260, brdf_w2, brdf_b2,
                                     out + (size_t)bpx0*128, 128, nullptr, 0, t);
}

extern "C" void kernel_launch(void* const* d_in, const int* in_sizes, int n_in,
                              void* d_out, int out_size, void* d_ws, size_t ws_size,
                              hipStream_t stream)
{
  (void)in_sizes; (void)n_in; (void)ws_size; (void)out_size;
  int i = 0;
  const float* rgb      = (const float*)d_in[i++];
  const float* fm       = (const float*)d_in[i++];
  const float* view_dir = (const float*)d_in[i++];
  const float* proj_err = (const float*)d_in[i++];
  const float* normal   = (const float*)d_in[i++];
  const float* DL       = (const float*)d_in[i++];
  const float* pbr_ln_g = (const float*)d_in[i++];
  const float* pbr_ln_b = (const float*)d_in[i++];
  const float* pbr_w1   = (const float*)d_in[i++];
  const float* pbr_b1   = (const float*)d_in[i++];
  const float* pbr_w2   = (const float*)d_in[i++];
  const float* pbr_b2   = (const float*)d_in[i++];
  const float* pbr_w3   = (const float*)d_in[i++];
  const float* pbr_b3   = (const float*)d_in[i++];
  const float* pbr_w4   = (const float*)d_in[i++];
  const float* pbr_b4   = (const float*)d_in[i++];
  const float* tv1_ln_g = (const float*)d_in[i++];
  const float* tv1_ln_b = (const float*)d_in[i++];
  const float* tv1_w    = (const float*)d_in[i++];
  const float* to1_w    = (const float*)d_in[i++];
  const float* to1_b    = (const float*)d_in[i++];
  const float* n1_ln_g  = (const float*)d_in[i++];
  const float* n1_ln_b  = (const float*)d_in[i++];
  const float* n1_w1    = (const float*)d_in[i++];
  const float* n1_b1    = (const float*)d_in[i++];
  const float* n1_w2    = (const float*)d_in[i++];
  const float* n1_b2    = (const float*)d_in[i++];
  const float* tv2_ln_g = (const float*)d_in[i++];
  const float* tv2_ln_b = (const float*)d_in[i++];
  const float* tv2_w    = (const float*)d_in[i++];
  const float* to2_w    = (const float*)d_in[i++];
  const float* to2_b    = (const float*)d_in[i++];
  const float* n2_ln_g  = (const float*)d_in[i++];
  const float* n2_ln_b  = (const float*)d_in[i++];
  const float* n2_w1    = (const float*)d_in[i++];
  const float* n2_b1    = (const float*)d_in[i++];
  const float* n2_w2    = (const float*)d_in[i++];
  const float* n2_b2    = (const float*)d_in[i++];
  const float* brdf_ln_g= (const float*)d_in[i++];
  const float* brdf_ln_b= (const float*)d_in[i++];
  const float* brdf_w1  = (const float*)d_in[i++];
  const float* brdf_b1  = (const float*)d_in[i++];
  const float* brdf_w2  = (const float*)d_in[i++];
  const float* brdf_b2  = (const float*)d_in[i++];

  float* feat = (float*)d_ws;

  mva_phaseA<<<dim3(NBA), dim3(NTA), 0, stream>>>(
      view_dir, normal, DL, pbr_ln_g, pbr_ln_b,
      pbr_w1, pbr_b1, pbr_w2, pbr_b2, pbr_w3, pbr_b3, pbr_w4, pbr_b4, feat);

  mva_phaseB<<<dim3(NBB), dim3(NTB), 0, stream>>>(
      rgb, fm, proj_err, feat,
      tv1_ln_g, tv1_ln_b, tv1_w, to1_w, to1_b,
      n1_ln_g, n1_ln_b, n1_w1, n1_b1, n1_w2, n1_b2,
      tv2_ln_g, tv2_ln_b, tv2_w, to2_w, to2_b,
      n2_ln_g, n2_ln_b, n2_w1, n2_b1, n2_w2, n2_b2,
      brdf_ln_g, brdf_ln_b, brdf_w1, brdf_b1, brdf_w2, brdf_b2,
      (float*)d_out);
}

// Round 8
// 1918.378 us; speedup vs baseline: 1.5467x; 1.5467x over previous
//
#include <hip/hip_runtime.h>
#include <math.h>

// MultiViewAggregation — round 8.
// A: PBR MLP, named-register activations (ext_vector_type v4); weights via
//    address_space(4) ext-vector pointers -> scalar s_load (SGPR operands).
// B: round-6 structure unchanged (4 px / 512 thr, 2-chain row-pair units).

#define NPIX 16384

__device__ __forceinline__ float elu_f(float x){ return x > 0.f ? x : (__expf(x) - 1.f); }
__device__ __forceinline__ float gelu_f(float x){ return 0.5f*x*(1.f + erff(x*0.70710678118654752f)); }

// ===================== Kernel A =====================
#define NTA 384
#define NBA (NPIX/4)

typedef float v4 __attribute__((ext_vector_type(4)));
#define AS4 __attribute__((address_space(4)))
typedef const AS4 v4*    cf4p;
typedef const AS4 float* cf1p;

__device__ __forceinline__ v4 elu4(v4 a){
  v4 r; r.x = elu_f(a.x); r.y = elu_f(a.y); r.z = elu_f(a.z); r.w = elu_f(a.w); return r;
}

#define FMA4(A, S, WV) { v4 _w = (WV); \
  A.x = fmaf((S), _w.x, A.x); A.y = fmaf((S), _w.y, A.y); \
  A.z = fmaf((S), _w.z, A.z); A.w = fmaf((S), _w.w, A.w); }

#define AK4W(A, Sq, W, base, LD) \
  FMA4(A, (Sq).x, W[(base)]) \
  FMA4(A, (Sq).y, W[(base)+(LD)]) \
  FMA4(A, (Sq).z, W[(base)+2*(LD)]) \
  FMA4(A, (Sq).w, W[(base)+3*(LD)])

#define COL64(A, W, B4, cb, S) { A = B4[cb]; \
  AK4W(A, S##0,  W,  0*64+(cb), 16) AK4W(A, S##1,  W,  1*64+(cb), 16) \
  AK4W(A, S##2,  W,  2*64+(cb), 16) AK4W(A, S##3,  W,  3*64+(cb), 16) \
  AK4W(A, S##4,  W,  4*64+(cb), 16) AK4W(A, S##5,  W,  5*64+(cb), 16) \
  AK4W(A, S##6,  W,  6*64+(cb), 16) AK4W(A, S##7,  W,  7*64+(cb), 16) \
  AK4W(A, S##8,  W,  8*64+(cb), 16) AK4W(A, S##9,  W,  9*64+(cb), 16) \
  AK4W(A, S##10, W, 10*64+(cb), 16) AK4W(A, S##11, W, 11*64+(cb), 16) \
  AK4W(A, S##12, W, 12*64+(cb), 16) AK4W(A, S##13, W, 13*64+(cb), 16) \
  AK4W(A, S##14, W, 14*64+(cb), 16) AK4W(A, S##15, W, 15*64+(cb), 16) }

#define LAYER64(D, S, W, B4) { v4 _a; \
  COL64(_a, W, B4, 0,  S) D##0  = elu4(_a); \
  COL64(_a, W, B4, 1,  S) D##1  = elu4(_a); \
  COL64(_a, W, B4, 2,  S) D##2  = elu4(_a); \
  COL64(_a, W, B4, 3,  S) D##3  = elu4(_a); \
  COL64(_a, W, B4, 4,  S) D##4  = elu4(_a); \
  COL64(_a, W, B4, 5,  S) D##5  = elu4(_a); \
  COL64(_a, W, B4, 6,  S) D##6  = elu4(_a); \
  COL64(_a, W, B4, 7,  S) D##7  = elu4(_a); \
  COL64(_a, W, B4, 8,  S) D##8  = elu4(_a); \
  COL64(_a, W, B4, 9,  S) D##9  = elu4(_a); \
  COL64(_a, W, B4, 10, S) D##10 = elu4(_a); \
  COL64(_a, W, B4, 11, S) D##11 = elu4(_a); \
  COL64(_a, W, B4, 12, S) D##12 = elu4(_a); \
  COL64(_a, W, B4, 13, S) D##13 = elu4(_a); \
  COL64(_a, W, B4, 14, S) D##14 = elu4(_a); \
  COL64(_a, W, B4, 15, S) D##15 = elu4(_a); }

#define COL32(A, W, B4, cb, S) { A = B4[cb]; \
  AK4W(A, S##0,  W,  0*32+(cb), 8) AK4W(A, S##1,  W,  1*32+(cb), 8) \
  AK4W(A, S##2,  W,  2*32+(cb), 8) AK4W(A, S##3,  W,  3*32+(cb), 8) \
  AK4W(A, S##4,  W,  4*32+(cb), 8) AK4W(A, S##5,  W,  5*32+(cb), 8) \
  AK4W(A, S##6,  W,  6*32+(cb), 8) AK4W(A, S##7,  W,  7*32+(cb), 8) \
  AK4W(A, S##8,  W,  8*32+(cb), 8) AK4W(A, S##9,  W,  9*32+(cb), 8) \
  AK4W(A, S##10, W, 10*32+(cb), 8) AK4W(A, S##11, W, 11*32+(cb), 8) \
  AK4W(A, S##12, W, 12*32+(cb), 8) AK4W(A, S##13, W, 13*32+(cb), 8) \
  AK4W(A, S##14, W, 14*32+(cb), 8) AK4W(A, S##15, W, 15*32+(cb), 8) }

#define COLL1(A, B4, cb) { A = B4[cb]; \
  FMA4(A, xl0, W1v[ 0+(cb)]) FMA4(A, xl1, W1v[16+(cb)]) \
  FMA4(A, xl2, W1v[32+(cb)]) FMA4(A, xl3, W1v[48+(cb)]) \
  FMA4(A, xl4, W1v[64+(cb)]) FMA4(A, xl5, W1v[80+(cb)]) \
  FMA4(A, xl6, W1v[96+(cb)]) }

#define SHF32(A) { A.x += __shfl_xor(A.x, 32); A.y += __shfl_xor(A.y, 32); \
                   A.z += __shfl_xor(A.z, 32); A.w += __shfl_xor(A.w, 32); }

#define ST4(p, o, A) { (p)[(o)] = A.x; (p)[(o)+1] = A.y; (p)[(o)+2] = A.z; (p)[(o)+3] = A.w; }

__global__ __launch_bounds__(NTA)
void mva_phaseA(const float* __restrict__ view_dir, const float* __restrict__ normal,
                const float* __restrict__ DL,
                const float* __restrict__ ln_g, const float* __restrict__ ln_b,
                const float* __restrict__ w1, const float* __restrict__ b1,
                const float* __restrict__ w2, const float* __restrict__ b2,
                const float* __restrict__ w3, const float* __restrict__ b3,
                const float* __restrict__ w4, const float* __restrict__ b4,
                float* __restrict__ feat)
{
  __shared__ float fb[6*32*33];
  const int t   = threadIdx.x;
  const int pxv = t & 31;
  const int sg  = t >> 5;
  const int px  = blockIdx.x*4 + (pxv >> 3);
  const int view = pxv & 7;

  // constant-space (scalar) views of the weights — uniform addresses -> s_load
  cf4p W1v = (cf4p)(unsigned long long)w1;
  cf4p B1v = (cf4p)(unsigned long long)b1;
  cf4p W2v = (cf4p)(unsigned long long)w2;
  cf4p B2v = (cf4p)(unsigned long long)b2;
  cf4p W3v = (cf4p)(unsigned long long)w3;
  cf4p B3v = (cf4p)(unsigned long long)b3;
  cf4p W4v = (cf4p)(unsigned long long)w4;
  cf4p B4v = (cf4p)(unsigned long long)b4;
  cf1p LG  = (cf1p)(unsigned long long)ln_g;
  cf1p LB  = (cf1p)(unsigned long long)ln_b;

  const float nm0 = normal[px*3+0], nm1 = normal[px*3+1], nm2 = normal[px*3+2];
  const float* vd = view_dir + (px*8 + view)*3;
  const float vd0 = vd[0], vd1 = vd[1], vd2 = vd[2];
  const float* dl = DL + px*84 + sg*7;
  const float d0=dl[0], d1=dl[1], d2=dl[2], d3=dl[3], d4=dl[4], d5=dl[5], d6=dl[6];

  const float DLdotN = d0*nm0 + d1*nm1 + d2*nm2;
  const float hv     = (d0*vd0 + d1*vd1 + d2*vd2 + 1.f)*0.5f;
  const float fres   = exp2f((-5.55472f*hv - 6.98316f)*hv);
  const float VdotN  = vd0*nm0 + vd1*nm1 + vd2*nm2;

  const float x0 = DLdotN, x1 = d3, x2 = d4, x3 = d5, x4 = d6, x5 = fres, x6 = VdotN;
  const float m  = (x0+x1+x2+x3+x4+x5+x6)*(1.f/7.f);
  float q, var = 0.f;
  q = x0-m; var += q*q; q = x1-m; var += q*q; q = x2-m; var += q*q;
  q = x3-m; var += q*q; q = x4-m; var += q*q; q = x5-m; var += q*q;
  q = x6-m; var += q*q;
  const float rs = rsqrtf(var*(1.f/7.f) + 1e-5f);
  const float xl0 = (x0-m)*rs*LG[0] + LB[0];
  const float xl1 = (x1-m)*rs*LG[1] + LB[1];
  const float xl2 = (x2-m)*rs*LG[2] + LB[2];
  const float xl3 = (x3-m)*rs*LG[3] + LB[3];
  const float xl4 = (x4-m)*rs*LG[4] + LB[4];
  const float xl5 = (x5-m)*rs*LG[5] + LB[5];
  const float xl6 = (x6-m)*rs*LG[6] + LB[6];

  v4 Y0,Y1,Y2,Y3,Y4,Y5,Y6,Y7,Y8,Y9,Y10,Y11,Y12,Y13,Y14,Y15;
  { v4 _a;
    COLL1(_a, B1v, 0)  Y0  = elu4(_a);
    COLL1(_a, B1v, 1)  Y1  = elu4(_a);
    COLL1(_a, B1v, 2)  Y2  = elu4(_a);
    COLL1(_a, B1v, 3)  Y3  = elu4(_a);
    COLL1(_a, B1v, 4)  Y4  = elu4(_a);
    COLL1(_a, B1v, 5)  Y5  = elu4(_a);
    COLL1(_a, B1v, 6)  Y6  = elu4(_a);
    COLL1(_a, B1v, 7)  Y7  = elu4(_a);
    COLL1(_a, B1v, 8)  Y8  = elu4(_a);
    COLL1(_a, B1v, 9)  Y9  = elu4(_a);
    COLL1(_a, B1v, 10) Y10 = elu4(_a);
    COLL1(_a, B1v, 11) Y11 = elu4(_a);
    COLL1(_a, B1v, 12) Y12 = elu4(_a);
    COLL1(_a, B1v, 13) Y13 = elu4(_a);
    COLL1(_a, B1v, 14) Y14 = elu4(_a);
    COLL1(_a, B1v, 15) Y15 = elu4(_a);
  }

  v4 Z0,Z1,Z2,Z3,Z4,Z5,Z6,Z7,Z8,Z9,Z10,Z11,Z12,Z13,Z14,Z15;
  LAYER64(Z, Y, W2v, B2v)
  LAYER64(Y, Z, W3v, B3v)

  v4 F0,F1,F2,F3,F4,F5,F6,F7;
  { v4 _a;
    COL32(_a, W4v, B4v, 0, Y) F0 = _a;
    COL32(_a, W4v, B4v, 1, Y) F1 = _a;
    COL32(_a, W4v, B4v, 2, Y) F2 = _a;
    COL32(_a, W4v, B4v, 3, Y) F3 = _a;
    COL32(_a, W4v, B4v, 4, Y) F4 = _a;
    COL32(_a, W4v, B4v, 5, Y) F5 = _a;
    COL32(_a, W4v, B4v, 6, Y) F6 = _a;
    COL32(_a, W4v, B4v, 7, Y) F7 = _a;
  }

  SHF32(F0) SHF32(F1) SHF32(F2) SHF32(F3)
  SHF32(F4) SHF32(F5) SHF32(F6) SHF32(F7)

  if ((t & 63) < 32){
    float* row = fb + (t>>6)*1056 + pxv*33;
    ST4(row, 0,  F0) ST4(row, 4,  F1) ST4(row, 8,  F2) ST4(row, 12, F3)
    ST4(row, 16, F4) ST4(row, 20, F5) ST4(row, 24, F6) ST4(row, 28, F7)
  }
  __syncthreads();

  for (int u = t; u < 1024; u += NTA){
    const int pv = u >> 5, c = u & 31;
    float s = 0.f;
    #pragma unroll
    for (int w = 0; w < 6; ++w) s += fb[w*1056 + pv*33 + c];
    feat[(size_t)blockIdx.x*1024 + u] = s;
  }
}

// ===================== Kernel B (round-6, unchanged) =====================
#define NTB 512
#define NBB (NPIX/4)

constexpr int BXIN  = 0;      // [32][100]
constexpr int BXCUR = 3200;   // [32][100]
constexpr int BXLN  = 6400;   // [32][100]
constexpr int BHID  = 9600;   // [32][132] / [4][260]
constexpr int BVB   = 13824;  // [32][36]
constexpr int BMEAN = 14976;  // [4][32]
constexpr int BVAR  = 15104;  // [4][32]
constexpr int BWGT  = 15232;  // 32
constexpr int BXS   = 15264;  // [4][96]
constexpr int BXSLN = 15648;  // [4][96]
constexpr int BTOT  = 16032;  // 64128 B

__device__ __forceinline__ void fma4(float4& a, float s, const float4 w){
  a.x = fmaf(s, w.x, a.x); a.y = fmaf(s, w.y, a.y);
  a.z = fmaf(s, w.z, a.z); a.w = fmaf(s, w.w, a.w);
}

__device__ __forceinline__ void ln32(const float* __restrict__ in,
                                     float* __restrict__ out,
                                     const float* __restrict__ g, const float* __restrict__ b,
                                     int t)
{
  if (t < 256){
    const int r = t >> 3, l8 = t & 7;
    const float* row = in + r*100;
    float vals[12]; int cols[12];
    float s1 = 0.f, s2 = 0.f;
    #pragma unroll
    for (int i = 0; i < 12; ++i){
      int c = l8 + 8*i + 8*(r & 7); if (c >= 96) c -= 96;
      float a = row[c];
      cols[i] = c; vals[i] = a; s1 += a; s2 += a*a;
    }
    s1 += __shfl_xor(s1, 1); s2 += __shfl_xor(s2, 1);
    s1 += __shfl_xor(s1, 2); s2 += __shfl_xor(s2, 2);
    s1 += __shfl_xor(s1, 4); s2 += __shfl_xor(s2, 4);
    float mean = s1*(1.f/96.f);
    float var  = s2*(1.f/96.f) - mean*mean;
    float rsd = rsqrtf(var + 1e-5f);
    float* orow = out + r*100;
    #pragma unroll
    for (int i = 0; i < 12; ++i){
      int c = cols[i];
      orow[c] = (vals[i]-mean)*rsd*g[c] + b[c];
    }
  }
}

__device__ __forceinline__ void lnP(const float* __restrict__ in,
                                    float* __restrict__ out,
                                    const float* __restrict__ g, const float* __restrict__ b,
                                    int t)
{
  if (t < 64){
    const int r = t >> 4, l = t & 15;
    const float* row = in + r*96;
    float vals[6];
    float s1 = 0.f, s2 = 0.f;
    #pragma unroll
    for (int i = 0; i < 6; ++i){
      float a = row[l + 16*i];
      vals[i] = a; s1 += a; s2 += a*a;
    }
    s1 += __shfl_xor(s1, 1); s2 += __shfl_xor(s2, 1);
    s1 += __shfl_xor(s1, 2); s2 += __shfl_xor(s2, 2);
    s1 += __shfl_xor(s1, 4); s2 += __shfl_xor(s2, 4);
    s1 += __shfl_xor(s1, 8); s2 += __shfl_xor(s2, 8);
    float mean = s1*(1.f/96.f);
    float var  = s2*(1.f/96.f) - mean*mean;
    float rsd = rsqrtf(var + 1e-5f);
    float* orow = out + r*96;
    #pragma unroll
    for (int i = 0; i < 6; ++i){
      int c = l + 16*i;
      orow[c] = (vals[i]-mean)*rsd*g[c] + b[c];
    }
  }
}

template<int K, int C, int LDW, bool GELU, bool HASB, bool RES, bool ACC>
__device__ __forceinline__ void mmR32(const float* __restrict__ inb, int S,
                                      const float* __restrict__ Wg, const float* __restrict__ bg,
                                      float* __restrict__ outb, int So,
                                      const float* __restrict__ residb, int Sr, int t)
{
  constexpr int C4 = C/4;
  const float4* __restrict__ W4 = (const float4*)Wg;
  for (int gi = t; gi < C4*16; gi += NTB){
    const int rp = gi & 15, c4 = gi >> 4;
    const float2* x0 = (const float2*)(inb + (2*rp)*S);
    const float2* x1 = (const float2*)(inb + (2*rp+1)*S);
    float4 a0 = HASB ? ((const float4*)bg)[c4] : make_float4(0.f,0.f,0.f,0.f);
    float4 a1 = a0;
    #pragma unroll 8
    for (int k2 = 0; k2 < K/2; ++k2){
      float2 xa = x0[k2], xb = x1[k2];
      float4 wA = W4[(2*k2)*(LDW/4) + c4];
      float4 wB = W4[(2*k2+1)*(LDW/4) + c4];
      fma4(a0, xa.x, wA); fma4(a0, xa.y, wB);
      fma4(a1, xb.x, wA); fma4(a1, xb.y, wB);
    }
    if (GELU){
      a0.x=gelu_f(a0.x); a0.y=gelu_f(a0.y); a0.z=gelu_f(a0.z); a0.w=gelu_f(a0.w);
      a1.x=gelu_f(a1.x); a1.y=gelu_f(a1.y); a1.z=gelu_f(a1.z); a1.w=gelu_f(a1.w);
    }
    if (RES){
      const float* r0 = residb + (2*rp)*Sr + 4*c4;
      const float* r1 = residb + (2*rp+1)*Sr + 4*c4;
      a0.x += r0[0]; a0.y += r0[1]; a0.z += r0[2]; a0.w += r0[3];
      a1.x += r1[0]; a1.y += r1[1]; a1.z += r1[2]; a1.w += r1[3];
    }
    float* o0 = outb + (2*rp)*So + 4*c4;
    float* o1 = outb + (2*rp+1)*So + 4*c4;
    if (ACC){
      a0.x += o0[0]; a0.y += o0[1]; a0.z += o0[2]; a0.w += o0[3];
      a1.x += o1[0]; a1.y += o1[1]; a1.z += o1[2]; a1.w += o1[3];
    }
    o0[0]=a0.x; o0[1]=a0.y; o0[2]=a0.z; o0[3]=a0.w;
    o1[0]=a1.x; o1[1]=a1.y; o1[2]=a1.z; o1[3]=a1.w;
  }
}

template<int K, int C, int LDW, bool GELU, bool HASB, bool RES>
__device__ __forceinline__ void mmP4(const float* __restrict__ inb, int S,
                                     const float* __restrict__ Wg, const float* __restrict__ bg,
                                     float* __restrict__ outb, int So,
                                     const float* __restrict__ residb, int Sr, int t)
{
  for (int gi = t; gi < 4*C; gi += NTB){
    const int kq = gi & 7, c2 = gi >> 3;
    const int k0 = kq*(K/8);
    float2 a0 = make_float2(0.f,0.f), a1 = a0, a2 = a0, a3 = a0;
    #pragma unroll 4
    for (int kk = 0; kk < K/8; ++kk){
      const int k = k0 + kk;
      const float2 w = *(const float2*)(Wg + k*LDW + 2*c2);
      const float xA = inb[0*S+k], xB = inb[1*S+k], xC = inb[2*S+k], xD = inb[3*S+k];
      a0.x = fmaf(xA, w.x, a0.x); a0.y = fmaf(xA, w.y, a0.y);
      a1.x = fmaf(xB, w.x, a1.x); a1.y = fmaf(xB, w.y, a1.y);
      a2.x = fmaf(xC, w.x, a2.x); a2.y = fmaf(xC, w.y, a2.y);
      a3.x = fmaf(xD, w.x, a3.x); a3.y = fmaf(xD, w.y, a3.y);
    }
    #pragma unroll
    for (int off = 1; off < 8; off <<= 1){
      a0.x += __shfl_xor(a0.x, off); a0.y += __shfl_xor(a0.y, off);
      a1.x += __shfl_xor(a1.x, off); a1.y += __shfl_xor(a1.y, off);
      a2.x += __shfl_xor(a2.x, off); a2.y += __shfl_xor(a2.y, off);
      a3.x += __shfl_xor(a3.x, off); a3.y += __shfl_xor(a3.y, off);
    }
    if (kq == 0){
      if (HASB){
        const float bx = bg[2*c2], by = bg[2*c2+1];
        a0.x+=bx; a0.y+=by; a1.x+=bx; a1.y+=by;
        a2.x+=bx; a2.y+=by; a3.x+=bx; a3.y+=by;
      }
      if (GELU){
        a0.x=gelu_f(a0.x); a0.y=gelu_f(a0.y); a1.x=gelu_f(a1.x); a1.y=gelu_f(a1.y);
        a2.x=gelu_f(a2.x); a2.y=gelu_f(a2.y); a3.x=gelu_f(a3.x); a3.y=gelu_f(a3.y);
      }
      if (RES){
        a0.x += residb[0*Sr+2*c2]; a0.y += residb[0*Sr+2*c2+1];
        a1.x += residb[1*Sr+2*c2]; a1.y += residb[1*Sr+2*c2+1];
        a2.x += residb[2*Sr+2*c2]; a2.y += residb[2*Sr+2*c2+1];
        a3.x += residb[3*Sr+2*c2]; a3.y += residb[3*Sr+2*c2+1];
      }
      outb[0*So+2*c2] = a0.x; outb[0*So+2*c2+1] = a0.y;
      outb[1*So+2*c2] = a1.x; outb[1*So+2*c2+1] = a1.y;
      outb[2*So+2*c2] = a2.x; outb[2*So+2*c2+1] = a2.y;
      outb[3*So+2*c2] = a3.x; outb[3*So+2*c2+1] = a3.y;
    }
  }
}

__global__ __launch_bounds__(NTB)
void mva_phaseB(const float* __restrict__ rgb, const float* __restrict__ fm,
                const float* __restrict__ proj_err, const float* __restrict__ feat,
                const float* __restrict__ tv1_ln_g, const float* __restrict__ tv1_ln_b,
                const float* __restrict__ tv1_w,
                const float* __restrict__ to1_w, const float* __restrict__ to1_b,
                const float* __restrict__ n1_ln_g, const float* __restrict__ n1_ln_b,
                const float* __restrict__ n1_w1, const float* __restrict__ n1_b1,
                const float* __restrict__ n1_w2, const float* __restrict__ n1_b2,
                const float* __restrict__ tv2_ln_g, const float* __restrict__ tv2_ln_b,
                const float* __restrict__ tv2_w,
                const float* __restrict__ to2_w, const float* __restrict__ to2_b,
                const float* __restrict__ n2_ln_g, const float* __restrict__ n2_ln_b,
                const float* __restrict__ n2_w1, const float* __restrict__ n2_b1,
                const float* __restrict__ n2_w2, const float* __restrict__ n2_b2,
                const float* __restrict__ brdf_ln_g, const float* __restrict__ brdf_ln_b,
                const float* __restrict__ brdf_w1, const float* __restrict__ brdf_b1,
                const float* __restrict__ brdf_w2, const float* __restrict__ brdf_b2,
                float* __restrict__ out)
{
  __shared__ __align__(16) float smem[BTOT];
  const int t = threadIdx.x;
  const int bpx0 = blockIdx.x*4;

  for (int u = t; u < 2048; u += NTB){
    const int r = u >> 6, k = u & 63;
    const int pl = r >> 3, v = r & 7;
    float val = (k < 3) ? rgb[((bpx0+pl)*8 + v)*3 + k]
                        : fm[(bpx0+pl)*61 + (k-3)];
    smem[BXIN + r*100 + k] = val;
  }
  for (int u = t; u < 1024; u += NTB){
    const int r = u >> 5, c = u & 31;
    smem[BXIN + r*100 + 64 + c] = feat[(size_t)blockIdx.x*1024 + u];
  }
  if (t < 32){
    float pe = proj_err[(bpx0 + (t>>3))*8 + (t&7)];
    float wraw = fmaxf(-log10f(fabsf(pe) + 1e-6f), 0.f);
    float s = wraw;
    s += __shfl_xor(s, 1); s += __shfl_xor(s, 2); s += __shfl_xor(s, 4);
    smem[BWGT + t] = wraw / (s + 1e-6f);
  }
  __syncthreads();

  // tv1
  ln32(smem+BXIN, smem+BXLN, tv1_ln_g, tv1_ln_b, t);
  __syncthreads();
  mmR32<96,32,32,false,false,false,false>(smem+BXLN, 100, tv1_w, nullptr, smem+BVB, 36, nullptr, 0, t);
  __syncthreads();
  if (t < 128){
    const int pl = t >> 5, c = t & 31;
    const float* wn = smem + BWGT + pl*8;
    float m = 0.f;
    #pragma unroll
    for (int v = 0; v < 8; ++v) m += wn[v]*smem[BVB + (pl*8+v)*36 + c];
    float vv = 0.f;
    #pragma unroll
    for (int v = 0; v < 8; ++v){ float d = smem[BVB + (pl*8+v)*36 + c] - m; vv += wn[v]*d*d; }
    smem[BMEAN + pl*32 + c] = m;
    smem[BVAR  + pl*32 + c] = vv;
  }
  __syncthreads();
  for (int u = t; u < 3072; u += NTB){
    const int r = u & 31, c = u >> 5;
    const int pl = r >> 3;
    float val = (c < 32) ? smem[BVB + r*36 + c]
              : (c < 64) ? smem[BMEAN + pl*32 + (c-32)]
                         : smem[BVAR + pl*32 + (c-64)];
    smem[BXLN + r*100 + c] = val;
  }
  __syncthreads();
  mmR32<96,96,96,false,true,true,false>(smem+BXLN, 100, to1_w, to1_b, smem+BXCUR, 100, smem+BXIN, 100, t);
  __syncthreads();

  // n1 (two 128-chunks)
  ln32(smem+BXCUR, smem+BXLN, n1_ln_g, n1_ln_b, t);
  __syncthreads();
  mmR32<96,128,256,true,true,false,false>(smem+BXLN, 100, n1_w1, n1_b1, smem+BHID, 132, nullptr, 0, t);
  __syncthreads();
  mmR32<128,96,96,false,true,true,false>(smem+BHID, 132, n1_w2, n1_b2, smem+BXCUR, 100, smem+BXIN, 100, t);
  __syncthreads();
  mmR32<96,128,256,true,true,false,false>(smem+BXLN, 100, n1_w1 + 128, n1_b1 + 128, smem+BHID, 132, nullptr, 0, t);
  __syncthreads();
  mmR32<128,96,96,false,false,false,true>(smem+BHID, 132, n1_w2 + 128*96, nullptr, smem+BXCUR, 100, nullptr, 0, t);
  __syncthreads();

  // tv2 + stats
  ln32(smem+BXCUR, smem+BXLN, tv2_ln_g, tv2_ln_b, t);
  __syncthreads();
  mmR32<96,32,32,false,false,false,false>(smem+BXLN, 100, tv2_w, nullptr, smem+BVB, 36, nullptr, 0, t);
  __syncthreads();
  if (t < 128){
    const int pl = t >> 5, c = t & 31;
    const float* wn = smem + BWGT + pl*8;
    float m = 0.f;
    #pragma unroll
    for (int v = 0; v < 8; ++v) m += wn[v]*smem[BVB + (pl*8+v)*36 + c];
    float vv = 0.f;
    #pragma unroll
    for (int v = 0; v < 8; ++v){ float d = smem[BVB + (pl*8+v)*36 + c] - m; vv += wn[v]*d*d; }
    smem[BMEAN + pl*32 + c] = m;
    smem[BVAR  + pl*32 + c] = vv;
  }
  __syncthreads();
  if (t < 384){
    const int pl = t / 96, k = t - pl*96;
    float val = (k < 32) ? smem[BVB + (pl*8)*36 + k]
              : (k < 64) ? smem[BMEAN + pl*32 + (k-32)]
                         : smem[BVAR + pl*32 + (k-64)];
    smem[BXSLN + pl*96 + k] = val;
  }
  __syncthreads();
  mmP4<96,96,96,false,true,true>(smem+BXSLN, 96, to2_w, to2_b, smem+BXS, 96, smem+BXIN, 800, t);
  __syncthreads();

  // n2
  lnP(smem+BXS, smem+BXSLN, n2_ln_g, n2_ln_b, t);
  __syncthreads();
  mmP4<96,256,256,true,true,false>(smem+BXSLN, 96, n2_w1, n2_b1, smem+BHID, 260, nullptr, 0, t);
  __syncthreads();
  mmP4<256,96,96,false,true,true>(smem+BHID, 260, n2_w2, n2_b2, smem+BXS, 96, smem+BXIN, 800, t);
  __syncthreads();

  // brdf
  lnP(smem+BXS, smem+BXSLN, brdf_ln_g, brdf_ln_b, t);
  __syncthreads();
  mmP4<96,128,128,true,true,false>(smem+BXSLN, 96, brdf_w1, brdf_b1, smem+BHID, 260, nullptr, 0, t);
  __syncthreads();
  mmP4<128,128,128,false,true,false>(smem+BHID, 260, brdf_w2, brdf_b2,
                                     out + (size_t)bpx0*128, 128, nullptr, 0, t);
}

extern "C" void kernel_launch(void* const* d_in, const int* in_sizes, int n_in,
                              void* d_out, int out_size, void* d_ws, size_t ws_size,
                              hipStream_t stream)
{
  (void)in_sizes; (void)n_in; (void)ws_size; (void)out_size;
  int i = 0;
  const float* rgb      = (const float*)d_in[i++];
  const float* fm       = (const float*)d_in[i++];
  const float* view_dir = (const float*)d_in[i++];
  const float* proj_err = (const float*)d_in[i++];
  const float* normal   = (const float*)d_in[i++];
  const float* DL       = (const float*)d_in[i++];
  const float* pbr_ln_g = (const float*)d_in[i++];
  const float* pbr_ln_b = (const float*)d_in[i++];
  const float* pbr_w1   = (const float*)d_in[i++];
  const float* pbr_b1   = (const float*)d_in[i++];
  const float* pbr_w2   = (const float*)d_in[i++];
  const float* pbr_b2   = (const float*)d_in[i++];
  const float* pbr_w3   = (const float*)d_in[i++];
  const float* pbr_b3   = (const float*)d_in[i++];
  const float* pbr_w4   = (const float*)d_in[i++];
  const float* pbr_b4   = (const float*)d_in[i++];
  const float* tv1_ln_g = (const float*)d_in[i++];
  const float* tv1_ln_b = (const float*)d_in[i++];
  const float* tv1_w    = (const float*)d_in[i++];
  const float* to1_w    = (const float*)d_in[i++];
  const float* to1_b    = (const float*)d_in[i++];
  const float* n1_ln_g  = (const float*)d_in[i++];
  const float* n1_ln_b  = (const float*)d_in[i++];
  const float* n1_w1    = (const float*)d_in[i++];
  const float* n1_b1    = (const float*)d_in[i++];
  const float* n1_w2    = (const float*)d_in[i++];
  const float* n1_b2    = (const float*)d_in[i++];
  const float* tv2_ln_g = (const float*)d_in[i++];
  const float* tv2_ln_b = (const float*)d_in[i++];
  const float* tv2_w    = (const float*)d_in[i++];
  const float* to2_w    = (const float*)d_in[i++];
  const float* to2_b    = (const float*)d_in[i++];
  const float* n2_ln_g  = (const float*)d_in[i++];
  const float* n2_ln_b  = (const float*)d_in[i++];
  const float* n2_w1    = (const float*)d_in[i++];
  const float* n2_b1    = (const float*)d_in[i++];
  const float* n2_w2    = (const float*)d_in[i++];
  const float* n2_b2    = (const float*)d_in[i++];
  const float* brdf_ln_g= (const float*)d_in[i++];
  const float* brdf_ln_b= (const float*)d_in[i++];
  const float* brdf_w1  = (const float*)d_in[i++];
  const float* brdf_b1  = (const float*)d_in[i++];
  const float* brdf_w2  = (const float*)d_in[i++];
  const float* brdf_b2  = (const float*)d_in[i++];

  float* feat = (float*)d_ws;

  mva_phaseA<<<dim3(NBA), dim3(NTA), 0, stream>>>(
      view_dir, normal, DL, pbr_ln_g, pbr_ln_b,
      pbr_w1, pbr_b1, pbr_w2, pbr_b2, pbr_w3, pbr_b3, pbr_w4, pbr_b4, feat);

  mva_phaseB<<<dim3(NBB), dim3(NTB), 0, stream>>>(
      rgb, fm, proj_err, feat,
      tv1_ln_g, tv1_ln_b, tv1_w, to1_w, to1_b,
      n1_ln_g, n1_ln_b, n1_w1, n1_b1, n1_w2, n1_b2,
      tv2_ln_g, tv2_ln_b, tv2_w, to2_w, to2_b,
      n2_ln_g, n2_ln_b, n2_w1, n2_b1, n2_w2, n2_b2,
      brdf_ln_g, brdf_ln_b, brdf_w1, brdf_b1, brdf_w2, brdf_b2,
      (float*)d_out);
}

// Round 9
// 1428.024 us; speedup vs baseline: 2.0778x; 1.3434x over previous
//
#include <hip/hip_runtime.h>
#include <math.h>

// MultiViewAggregation — round 9.
// A: round-8 (AS4 scalar weights, named v4 regs) unchanged.
// B1: per-view stages with LDS-staged weight chunks (broadcast ds_read,
//     conflict-free strides 102/134/38), 4 px / 512 thr.
// B2: per-pixel tail as 32-row blocks reusing mmR32; state via d_ws feat area.

#define NPIX 16384

__device__ __forceinline__ float elu_f(float x){ return x > 0.f ? x : (__expf(x) - 1.f); }
__device__ __forceinline__ float gelu_f(float x){ return 0.5f*x*(1.f + erff(x*0.70710678118654752f)); }

// ===================== Kernel A (round-8, unchanged) =====================
#define NTA 384
#define NBA (NPIX/4)

typedef float v4 __attribute__((ext_vector_type(4)));
#define AS4Q __attribute__((address_space(4)))
typedef const AS4Q v4*    cf4p;
typedef const AS4Q float* cf1p;

__device__ __forceinline__ v4 elu4(v4 a){
  v4 r; r.x = elu_f(a.x); r.y = elu_f(a.y); r.z = elu_f(a.z); r.w = elu_f(a.w); return r;
}

#define FMA4A(A, S, WV) { v4 _w = (WV); \
  A.x = fmaf((S), _w.x, A.x); A.y = fmaf((S), _w.y, A.y); \
  A.z = fmaf((S), _w.z, A.z); A.w = fmaf((S), _w.w, A.w); }

#define AK4W(A, Sq, W, base, LD) \
  FMA4A(A, (Sq).x, W[(base)]) \
  FMA4A(A, (Sq).y, W[(base)+(LD)]) \
  FMA4A(A, (Sq).z, W[(base)+2*(LD)]) \
  FMA4A(A, (Sq).w, W[(base)+3*(LD)])

#define COL64(A, W, B4, cb, S) { A = B4[cb]; \
  AK4W(A, S##0,  W,  0*64+(cb), 16) AK4W(A, S##1,  W,  1*64+(cb), 16) \
  AK4W(A, S##2,  W,  2*64+(cb), 16) AK4W(A, S##3,  W,  3*64+(cb), 16) \
  AK4W(A, S##4,  W,  4*64+(cb), 16) AK4W(A, S##5,  W,  5*64+(cb), 16) \
  AK4W(A, S##6,  W,  6*64+(cb), 16) AK4W(A, S##7,  W,  7*64+(cb), 16) \
  AK4W(A, S##8,  W,  8*64+(cb), 16) AK4W(A, S##9,  W,  9*64+(cb), 16) \
  AK4W(A, S##10, W, 10*64+(cb), 16) AK4W(A, S##11, W, 11*64+(cb), 16) \
  AK4W(A, S##12, W, 12*64+(cb), 16) AK4W(A, S##13, W, 13*64+(cb), 16) \
  AK4W(A, S##14, W, 14*64+(cb), 16) AK4W(A, S##15, W, 15*64+(cb), 16) }

#define LAYER64(D, S, W, B4) { v4 _a; \
  COL64(_a, W, B4, 0,  S) D##0  = elu4(_a); \
  COL64(_a, W, B4, 1,  S) D##1  = elu4(_a); \
  COL64(_a, W, B4, 2,  S) D##2  = elu4(_a); \
  COL64(_a, W, B4, 3,  S) D##3  = elu4(_a); \
  COL64(_a, W, B4, 4,  S) D##4  = elu4(_a); \
  COL64(_a, W, B4, 5,  S) D##5  = elu4(_a); \
  COL64(_a, W, B4, 6,  S) D##6  = elu4(_a); \
  COL64(_a, W, B4, 7,  S) D##7  = elu4(_a); \
  COL64(_a, W, B4, 8,  S) D##8  = elu4(_a); \
  COL64(_a, W, B4, 9,  S) D##9  = elu4(_a); \
  COL64(_a, W, B4, 10, S) D##10 = elu4(_a); \
  COL64(_a, W, B4, 11, S) D##11 = elu4(_a); \
  COL64(_a, W, B4, 12, S) D##12 = elu4(_a); \
  COL64(_a, W, B4, 13, S) D##13 = elu4(_a); \
  COL64(_a, W, B4, 14, S) D##14 = elu4(_a); \
  COL64(_a, W, B4, 15, S) D##15 = elu4(_a); }

#define COL32(A, W, B4, cb, S) { A = B4[cb]; \
  AK4W(A, S##0,  W,  0*32+(cb), 8) AK4W(A, S##1,  W,  1*32+(cb), 8) \
  AK4W(A, S##2,  W,  2*32+(cb), 8) AK4W(A, S##3,  W,  3*32+(cb), 8) \
  AK4W(A, S##4,  W,  4*32+(cb), 8) AK4W(A, S##5,  W,  5*32+(cb), 8) \
  AK4W(A, S##6,  W,  6*32+(cb), 8) AK4W(A, S##7,  W,  7*32+(cb), 8) \
  AK4W(A, S##8,  W,  8*32+(cb), 8) AK4W(A, S##9,  W,  9*32+(cb), 8) \
  AK4W(A, S##10, W, 10*32+(cb), 8) AK4W(A, S##11, W, 11*32+(cb), 8) \
  AK4W(A, S##12, W, 12*32+(cb), 8) AK4W(A, S##13, W, 13*32+(cb), 8) \
  AK4W(A, S##14, W, 14*32+(cb), 8) AK4W(A, S##15, W, 15*32+(cb), 8) }

#define COLL1(A, B4, cb) { A = B4[cb]; \
  FMA4A(A, xl0, W1v[ 0+(cb)]) FMA4A(A, xl1, W1v[16+(cb)]) \
  FMA4A(A, xl2, W1v[32+(cb)]) FMA4A(A, xl3, W1v[48+(cb)]) \
  FMA4A(A, xl4, W1v[64+(cb)]) FMA4A(A, xl5, W1v[80+(cb)]) \
  FMA4A(A, xl6, W1v[96+(cb)]) }

#define SHF32(A) { A.x += __shfl_xor(A.x, 32); A.y += __shfl_xor(A.y, 32); \
                   A.z += __shfl_xor(A.z, 32); A.w += __shfl_xor(A.w, 32); }

#define ST4(p, o, A) { (p)[(o)] = A.x; (p)[(o)+1] = A.y; (p)[(o)+2] = A.z; (p)[(o)+3] = A.w; }

__global__ __launch_bounds__(NTA)
void mva_phaseA(const float* __restrict__ view_dir, const float* __restrict__ normal,
                const float* __restrict__ DL,
                const float* __restrict__ ln_g, const float* __restrict__ ln_b,
                const float* __restrict__ w1, const float* __restrict__ b1,
                const float* __restrict__ w2, const float* __restrict__ b2,
                const float* __restrict__ w3, const float* __restrict__ b3,
                const float* __restrict__ w4, const float* __restrict__ b4,
                float* __restrict__ feat)
{
  __shared__ float fb[6*32*33];
  const int t   = threadIdx.x;
  const int pxv = t & 31;
  const int sg  = t >> 5;
  const int px  = blockIdx.x*4 + (pxv >> 3);
  const int view = pxv & 7;

  cf4p W1v = (cf4p)(unsigned long long)w1;
  cf4p B1v = (cf4p)(unsigned long long)b1;
  cf4p W2v = (cf4p)(unsigned long long)w2;
  cf4p B2v = (cf4p)(unsigned long long)b2;
  cf4p W3v = (cf4p)(unsigned long long)w3;
  cf4p B3v = (cf4p)(unsigned long long)b3;
  cf4p W4v = (cf4p)(unsigned long long)w4;
  cf4p B4v = (cf4p)(unsigned long long)b4;
  cf1p LG  = (cf1p)(unsigned long long)ln_g;
  cf1p LB  = (cf1p)(unsigned long long)ln_b;

  const float nm0 = normal[px*3+0], nm1 = normal[px*3+1], nm2 = normal[px*3+2];
  const float* vd = view_dir + (px*8 + view)*3;
  const float vd0 = vd[0], vd1 = vd[1], vd2 = vd[2];
  const float* dl = DL + px*84 + sg*7;
  const float d0=dl[0], d1=dl[1], d2=dl[2], d3=dl[3], d4=dl[4], d5=dl[5], d6=dl[6];

  const float DLdotN = d0*nm0 + d1*nm1 + d2*nm2;
  const float hv     = (d0*vd0 + d1*vd1 + d2*vd2 + 1.f)*0.5f;
  const float fres   = exp2f((-5.55472f*hv - 6.98316f)*hv);
  const float VdotN  = vd0*nm0 + vd1*nm1 + vd2*nm2;

  const float x0 = DLdotN, x1 = d3, x2 = d4, x3 = d5, x4 = d6, x5 = fres, x6 = VdotN;
  const float m  = (x0+x1+x2+x3+x4+x5+x6)*(1.f/7.f);
  float q, var = 0.f;
  q = x0-m; var += q*q; q = x1-m; var += q*q; q = x2-m; var += q*q;
  q = x3-m; var += q*q; q = x4-m; var += q*q; q = x5-m; var += q*q;
  q = x6-m; var += q*q;
  const float rs = rsqrtf(var*(1.f/7.f) + 1e-5f);
  const float xl0 = (x0-m)*rs*LG[0] + LB[0];
  const float xl1 = (x1-m)*rs*LG[1] + LB[1];
  const float xl2 = (x2-m)*rs*LG[2] + LB[2];
  const float xl3 = (x3-m)*rs*LG[3] + LB[3];
  const float xl4 = (x4-m)*rs*LG[4] + LB[4];
  const float xl5 = (x5-m)*rs*LG[5] + LB[5];
  const float xl6 = (x6-m)*rs*LG[6] + LB[6];

  v4 Y0,Y1,Y2,Y3,Y4,Y5,Y6,Y7,Y8,Y9,Y10,Y11,Y12,Y13,Y14,Y15;
  { v4 _a;
    COLL1(_a, B1v, 0)  Y0  = elu4(_a);
    COLL1(_a, B1v, 1)  Y1  = elu4(_a);
    COLL1(_a, B1v, 2)  Y2  = elu4(_a);
    COLL1(_a, B1v, 3)  Y3  = elu4(_a);
    COLL1(_a, B1v, 4)  Y4  = elu4(_a);
    COLL1(_a, B1v, 5)  Y5  = elu4(_a);
    COLL1(_a, B1v, 6)  Y6  = elu4(_a);
    COLL1(_a, B1v, 7)  Y7  = elu4(_a);
    COLL1(_a, B1v, 8)  Y8  = elu4(_a);
    COLL1(_a, B1v, 9)  Y9  = elu4(_a);
    COLL1(_a, B1v, 10) Y10 = elu4(_a);
    COLL1(_a, B1v, 11) Y11 = elu4(_a);
    COLL1(_a, B1v, 12) Y12 = elu4(_a);
    COLL1(_a, B1v, 13) Y13 = elu4(_a);
    COLL1(_a, B1v, 14) Y14 = elu4(_a);
    COLL1(_a, B1v, 15) Y15 = elu4(_a);
  }

  v4 Z0,Z1,Z2,Z3,Z4,Z5,Z6,Z7,Z8,Z9,Z10,Z11,Z12,Z13,Z14,Z15;
  LAYER64(Z, Y, W2v, B2v)
  LAYER64(Y, Z, W3v, B3v)

  v4 F0,F1,F2,F3,F4,F5,F6,F7;
  { v4 _a;
    COL32(_a, W4v, B4v, 0, Y) F0 = _a;
    COL32(_a, W4v, B4v, 1, Y) F1 = _a;
    COL32(_a, W4v, B4v, 2, Y) F2 = _a;
    COL32(_a, W4v, B4v, 3, Y) F3 = _a;
    COL32(_a, W4v, B4v, 4, Y) F4 = _a;
    COL32(_a, W4v, B4v, 5, Y) F5 = _a;
    COL32(_a, W4v, B4v, 6, Y) F6 = _a;
    COL32(_a, W4v, B4v, 7, Y) F7 = _a;
  }

  SHF32(F0) SHF32(F1) SHF32(F2) SHF32(F3)
  SHF32(F4) SHF32(F5) SHF32(F6) SHF32(F7)

  if ((t & 63) < 32){
    float* row = fb + (t>>6)*1056 + pxv*33;
    ST4(row, 0,  F0) ST4(row, 4,  F1) ST4(row, 8,  F2) ST4(row, 12, F3)
    ST4(row, 16, F4) ST4(row, 20, F5) ST4(row, 24, F6) ST4(row, 28, F7)
  }
  __syncthreads();

  for (int u = t; u < 1024; u += NTA){
    const int pv = u >> 5, c = u & 31;
    float s = 0.f;
    #pragma unroll
    for (int w = 0; w < 6; ++w) s += fb[w*1056 + pv*33 + c];
    feat[(size_t)blockIdx.x*1024 + u] = s;
  }
}

// ===================== Shared B machinery =====================
#define NTB 512

__device__ __forceinline__ void fma4(float4& a, float s, const float4 w){
  a.x = fmaf(s, w.x, a.x); a.y = fmaf(s, w.y, a.y);
  a.z = fmaf(s, w.z, a.z); a.w = fmaf(s, w.w, a.w);
}

// stage KK x CC weight block (global row stride LDWG floats, col offset c4off
// in float4 units) into LDS wbuf with row stride CC.
template<int KK, int CC, int LDWG>
__device__ __forceinline__ void stageW(const float* __restrict__ Wg, int c4off,
                                       float* __restrict__ wbuf, int t)
{
  constexpr int C4 = CC/4;
  constexpr int N4 = KK*C4;
  const float4* __restrict__ s = (const float4*)Wg;
  float4* d = (float4*)wbuf;
  for (int i = t; i < N4; i += NTB){
    const int k = i / C4, c4 = i - k*C4;
    d[i] = s[k*(LDWG/4) + c4off + c4];
  }
}

// LN of 32 rows x 96, parameterized strides, bank-staggered columns.
__device__ __forceinline__ void ln32s(const float* __restrict__ in, int Si,
                                      float* __restrict__ out, int So,
                                      const float* __restrict__ g, const float* __restrict__ b,
                                      int t)
{
  if (t < 256){
    const int r = t >> 3, l8 = t & 7;
    const float* row = in + r*Si;
    float vals[12]; int cols[12];
    float s1 = 0.f, s2 = 0.f;
    #pragma unroll
    for (int i = 0; i < 12; ++i){
      int c = l8 + 8*i + 8*(r & 7); if (c >= 96) c -= 96;
      float a = row[c];
      cols[i] = c; vals[i] = a; s1 += a; s2 += a*a;
    }
    s1 += __shfl_xor(s1, 1); s2 += __shfl_xor(s2, 1);
    s1 += __shfl_xor(s1, 2); s2 += __shfl_xor(s2, 2);
    s1 += __shfl_xor(s1, 4); s2 += __shfl_xor(s2, 4);
    float mean = s1*(1.f/96.f);
    float var  = s2*(1.f/96.f) - mean*mean;
    float rsd = rsqrtf(var + 1e-5f);
    float* orow = out + r*So;
    #pragma unroll
    for (int i = 0; i < 12; ++i){
      int c = cols[i];
      orow[c] = (vals[i]-mean)*rsd*g[c] + b[c];
    }
  }
}

// 32-row matmul; unit=(c4,row-pair); weights from LDS wbuf (stride LDW=CC).
template<int K, int C, int LDW, bool GELU, bool HASB, bool RES, bool ACC>
__device__ __forceinline__ void mmR32(const float* __restrict__ inb, int S,
                                      const float* __restrict__ Wl, const float* __restrict__ bg,
                                      float* __restrict__ outb, int So,
                                      const float* __restrict__ residb, int Sr, int t)
{
  constexpr int C4 = C/4;
  const float4* __restrict__ W4 = (const float4*)Wl;
  for (int gi = t; gi < C4*16; gi += NTB){
    const int rp = gi & 15, c4 = gi >> 4;
    const float2* x0 = (const float2*)(inb + (2*rp)*S);
    const float2* x1 = (const float2*)(inb + (2*rp+1)*S);
    float4 a0 = HASB ? ((const float4*)bg)[c4] : make_float4(0.f,0.f,0.f,0.f);
    float4 a1 = a0;
    #pragma unroll 8
    for (int k2 = 0; k2 < K/2; ++k2){
      float2 xa = x0[k2], xb = x1[k2];
      float4 wA = W4[(2*k2)*(LDW/4) + c4];
      float4 wB = W4[(2*k2+1)*(LDW/4) + c4];
      fma4(a0, xa.x, wA); fma4(a0, xa.y, wB);
      fma4(a1, xb.x, wA); fma4(a1, xb.y, wB);
    }
    if (GELU){
      a0.x=gelu_f(a0.x); a0.y=gelu_f(a0.y); a0.z=gelu_f(a0.z); a0.w=gelu_f(a0.w);
      a1.x=gelu_f(a1.x); a1.y=gelu_f(a1.y); a1.z=gelu_f(a1.z); a1.w=gelu_f(a1.w);
    }
    if (RES){
      const float* r0 = residb + (2*rp)*Sr + 4*c4;
      const float* r1 = residb + (2*rp+1)*Sr + 4*c4;
      a0.x += r0[0]; a0.y += r0[1]; a0.z += r0[2]; a0.w += r0[3];
      a1.x += r1[0]; a1.y += r1[1]; a1.z += r1[2]; a1.w += r1[3];
    }
    float* o0 = outb + (2*rp)*So + 4*c4;
    float* o1 = outb + (2*rp+1)*So + 4*c4;
    if (ACC){
      a0.x += o0[0]; a0.y += o0[1]; a0.z += o0[2]; a0.w += o0[3];
      a1.x += o1[0]; a1.y += o1[1]; a1.z += o1[2]; a1.w += o1[3];
    }
    o0[0]=a0.x; o0[1]=a0.y; o0[2]=a0.z; o0[3]=a0.w;
    o1[0]=a1.x; o1[1]=a1.y; o1[2]=a1.z; o1[3]=a1.w;
  }
}

// ===================== Kernel B1: per-view stages =====================
#define NBB1 (NPIX/4)
// LDS floats (strides: rows 102, hid 134, vb 38)
constexpr int BXIN  = 0;             // [32][102]
constexpr int BXCUR = 3264;          // [32][102]
constexpr int BXLN  = 6528;          // [32][102]
constexpr int BHID  = 9792;          // [32][134]
constexpr int BVB   = 14080;         // [32][38]
constexpr int BMEAN = 15296;         // [4][32]
constexpr int BVAR  = 15424;         // [4][32]
constexpr int BWGT  = 15552;         // 32
constexpr int BWBUF = 15584;         // 12288 max
constexpr int B1TOT = 27872;         // 111.5 KB

__global__ __launch_bounds__(NTB)
void mva_phaseB1(const float* __restrict__ rgb, const float* __restrict__ fm,
                 const float* __restrict__ proj_err, float* __restrict__ ws,
                 const float* __restrict__ tv1_ln_g, const float* __restrict__ tv1_ln_b,
                 const float* __restrict__ tv1_w,
                 const float* __restrict__ to1_w, const float* __restrict__ to1_b,
                 const float* __restrict__ n1_ln_g, const float* __restrict__ n1_ln_b,
                 const float* __restrict__ n1_w1, const float* __restrict__ n1_b1,
                 const float* __restrict__ n1_w2, const float* __restrict__ n1_b2,
                 const float* __restrict__ tv2_ln_g, const float* __restrict__ tv2_ln_b,
                 const float* __restrict__ tv2_w)
{
  __shared__ __align__(16) float smem[B1TOT];
  const int t = threadIdx.x;
  const int bpx0 = blockIdx.x*4;
  float* WB = smem + BWBUF;

  // assemble XIN (rows r = pl*8+v, stride 102) + wgt; stage tv1
  for (int u = t; u < 2048; u += NTB){
    const int r = u >> 6, k = u & 63;
    const int pl = r >> 3, v = r & 7;
    float val = (k < 3) ? rgb[((bpx0+pl)*8 + v)*3 + k]
                        : fm[(bpx0+pl)*61 + (k-3)];
    smem[BXIN + r*102 + k] = val;
  }
  for (int u = t; u < 1024; u += NTB){
    const int r = u >> 5, c = u & 31;
    smem[BXIN + r*102 + 64 + c] = ws[(size_t)blockIdx.x*1024 + u];
  }
  if (t < 32){
    float pe = proj_err[(bpx0 + (t>>3))*8 + (t&7)];
    float wraw = fmaxf(-log10f(fabsf(pe) + 1e-6f), 0.f);
    float s = wraw;
    s += __shfl_xor(s, 1); s += __shfl_xor(s, 2); s += __shfl_xor(s, 4);
    smem[BWGT + t] = wraw / (s + 1e-6f);
  }
  stageW<96,32,32>(tv1_w, 0, WB, t);
  __syncthreads();

  // tv1
  ln32s(smem+BXIN, 102, smem+BXLN, 102, tv1_ln_g, tv1_ln_b, t);
  __syncthreads();
  mmR32<96,32,32,false,false,false,false>(smem+BXLN, 102, WB, nullptr, smem+BVB, 38, nullptr, 0, t);
  __syncthreads();
  if (t < 128){
    const int pl = t >> 5, c = t & 31;
    const float* wn = smem + BWGT + pl*8;
    float m = 0.f;
    #pragma unroll
    for (int v = 0; v < 8; ++v) m += wn[v]*smem[BVB + (pl*8+v)*38 + c];
    float vv = 0.f;
    #pragma unroll
    for (int v = 0; v < 8; ++v){ float d = smem[BVB + (pl*8+v)*38 + c] - m; vv += wn[v]*d*d; }
    smem[BMEAN + pl*32 + c] = m;
    smem[BVAR  + pl*32 + c] = vv;
  }
  __syncthreads();
  // xcat -> BXLN ; stage to1
  for (int u = t; u < 3072; u += NTB){
    const int r = u & 31, c = u >> 5;
    const int pl = r >> 3;
    float val = (c < 32) ? smem[BVB + r*38 + c]
              : (c < 64) ? smem[BMEAN + pl*32 + (c-32)]
                         : smem[BVAR + pl*32 + (c-64)];
    smem[BXLN + r*102 + c] = val;
  }
  stageW<96,96,96>(to1_w, 0, WB, t);
  __syncthreads();
  mmR32<96,96,96,false,true,true,false>(smem+BXLN, 102, WB, to1_b, smem+BXCUR, 102, smem+BXIN, 102, t);
  __syncthreads();

  // n1: two 128-col chunks, each (w1 chunk -> HID gelu; w2 K-chunk -> XCUR)
  ln32s(smem+BXCUR, 102, smem+BXLN, 102, n1_ln_g, n1_ln_b, t);
  __syncthreads();
  stageW<96,128,256>(n1_w1, 0, WB, t);
  __syncthreads();
  mmR32<96,128,128,true,true,false,false>(smem+BXLN, 102, WB, n1_b1, smem+BHID, 134, nullptr, 0, t);
  __syncthreads();
  stageW<128,96,96>(n1_w2, 0, WB, t);
  __syncthreads();
  mmR32<128,96,96,false,false,false,false>(smem+BHID, 134, WB, nullptr, smem+BXCUR, 102, nullptr, 0, t);
  __syncthreads();
  stageW<96,128,256>(n1_w1, 32, WB, t);
  __syncthreads();
  mmR32<96,128,128,true,true,false,false>(smem+BXLN, 102, WB, n1_b1 + 128, smem+BHID, 134, nullptr, 0, t);
  __syncthreads();
  stageW<128,96,96>(n1_w2 + 128*96, 0, WB, t);
  __syncthreads();
  mmR32<128,96,96,false,true,true,true>(smem+BHID, 134, WB, n1_b2, smem+BXCUR, 102, smem+BXIN, 102, t);
  __syncthreads();

  // tv2 + stats2
  ln32s(smem+BXCUR, 102, smem+BXLN, 102, tv2_ln_g, tv2_ln_b, t);
  stageW<96,32,32>(tv2_w, 0, WB, t);
  __syncthreads();
  mmR32<96,32,32,false,false,false,false>(smem+BXLN, 102, WB, nullptr, smem+BVB, 38, nullptr, 0, t);
  __syncthreads();
  if (t < 128){
    const int pl = t >> 5, c = t & 31;
    const float* wn = smem + BWGT + pl*8;
    float m = 0.f;
    #pragma unroll
    for (int v = 0; v < 8; ++v) m += wn[v]*smem[BVB + (pl*8+v)*38 + c];
    float vv = 0.f;
    #pragma unroll
    for (int v = 0; v < 8; ++v){ float d = smem[BVB + (pl*8+v)*38 + c] - m; vv += wn[v]*d*d; }
    smem[BMEAN + pl*32 + c] = m;
    smem[BVAR  + pl*32 + c] = vv;
  }
  __syncthreads();
  // xcat2 per pixel -> ws (feat views 3..5 region, dead now)
  if (t < 384){
    const int pl = t / 96, c = t - pl*96;
    float val = (c < 32) ? smem[BVB + (pl*8)*38 + c]
              : (c < 64) ? smem[BMEAN + pl*32 + (c-32)]
                         : smem[BVAR + pl*32 + (c-64)];
    ws[(size_t)blockIdx.x*1024 + pl*256 + 96 + c] = val;
  }
}

// ===================== Kernel B2: per-pixel tail (32 px rows) =====================
#define NBB2 (NPIX/32)
constexpr int CXLN  = 0;             // [32][102]
constexpr int CXIN  = 3264;          // [32][102]
constexpr int CXS   = 6528;          // [32][102]
constexpr int CTMP  = 9792;          // [32][102]
constexpr int CHID  = 13056;         // [32][134]
constexpr int CWBUF = 17344;         // 12288 max
constexpr int B2TOT = 29632;         // 118.5 KB

__global__ __launch_bounds__(NTB)
void mva_phaseB2(const float* __restrict__ rgb, const float* __restrict__ fm,
                 const float* __restrict__ ws,
                 const float* __restrict__ to2_w, const float* __restrict__ to2_b,
                 const float* __restrict__ n2_ln_g, const float* __restrict__ n2_ln_b,
                 const float* __restrict__ n2_w1, const float* __restrict__ n2_b1,
                 const float* __restrict__ n2_w2, const float* __restrict__ n2_b2,
                 const float* __restrict__ brdf_ln_g, const float* __restrict__ brdf_ln_b,
                 const float* __restrict__ brdf_w1, const float* __restrict__ brdf_b1,
                 const float* __restrict__ brdf_w2, const float* __restrict__ brdf_b2,
                 float* __restrict__ out)
{
  __shared__ __align__(16) float smem[B2TOT];
  const int t = threadIdx.x;
  const int bpx0 = blockIdx.x*32;
  float* WB = smem + CWBUF;

  // load xcat2 rows + xin0 resid rows
  for (int u = t; u < 3072; u += NTB){
    const int r = u / 96, c = u - r*96;
    const int px = bpx0 + r;
    const size_t ab = ((size_t)(px >> 2))*1024 + (size_t)(px & 3)*256;
    smem[CXLN + r*102 + c] = ws[ab + 96 + c];
    float xv = (c < 3)  ? rgb[((size_t)px*8)*3 + c]
             : (c < 64) ? fm[(size_t)px*61 + (c-3)]
                        : ws[ab + (c-64)];        // feat view0
    smem[CXIN + r*102 + c] = xv;
  }
  stageW<96,96,96>(to2_w, 0, WB, t);
  __syncthreads();

  // to2: xs = xcat2 @ to2_w + b + xin0
  mmR32<96,96,96,false,true,true,false>(smem+CXLN, 102, WB, to2_b, smem+CXS, 102, smem+CXIN, 102, t);
  __syncthreads();

  // n2
  ln32s(smem+CXS, 102, smem+CXLN, 102, n2_ln_g, n2_ln_b, t);
  __syncthreads();
  stageW<96,128,256>(n2_w1, 0, WB, t);
  __syncthreads();
  mmR32<96,128,128,true,true,false,false>(smem+CXLN, 102, WB, n2_b1, smem+CHID, 134, nullptr, 0, t);
  __syncthreads();
  stageW<128,96,96>(n2_w2, 0, WB, t);
  __syncthreads();
  mmR32<128,96,96,false,false,false,false>(smem+CHID, 134, WB, nullptr, smem+CTMP, 102, nullptr, 0, t);
  __syncthreads();
  stageW<96,128,256>(n2_w1, 32, WB, t);
  __syncthreads();
  mmR32<96,128,128,true,true,false,false>(smem+CXLN, 102, WB, n2_b1 + 128, smem+CHID, 134, nullptr, 0, t);
  __syncthreads();
  stageW<128,96,96>(n2_w2 + 128*96, 0, WB, t);
  __syncthreads();
  mmR32<128,96,96,false,true,true,true>(smem+CHID, 134, WB, n2_b2, smem+CTMP, 102, smem+CXIN, 102, t);
  __syncthreads();

  // brdf
  ln32s(smem+CTMP, 102, smem+CXLN, 102, brdf_ln_g, brdf_ln_b, t);
  __syncthreads();
  stageW<96,128,128>(brdf_w1, 0, WB, t);
  __syncthreads();
  mmR32<96,128,128,true,true,false,false>(smem+CXLN, 102, WB, brdf_b1, smem+CHID, 134, nullptr, 0, t);
  __syncthreads();
  float* outp = out + (size_t)bpx0*128;
  stageW<128,64,128>(brdf_w2, 0, WB, t);
  __syncthreads();
  mmR32<128,64,64,false,true,false,false>(smem+CHID, 134, WB, brdf_b2, outp, 128, nullptr, 0, t);
  __syncthreads();
  stageW<128,64,128>(brdf_w2, 16, WB, t);
  __syncthreads();
  mmR32<128,64,64,false,true,false,false>(smem+CHID, 134, WB, brdf_b2 + 64, outp + 64, 128, nullptr, 0, t);
}

extern "C" void kernel_launch(void* const* d_in, const int* in_sizes, int n_in,
                              void* d_out, int out_size, void* d_ws, size_t ws_size,
                              hipStream_t stream)
{
  (void)in_sizes; (void)n_in; (void)ws_size; (void)out_size;
  int i = 0;
  const float* rgb      = (const float*)d_in[i++];
  const float* fm       = (const float*)d_in[i++];
  const float* view_dir = (const float*)d_in[i++];
  const float* proj_err = (const float*)d_in[i++];
  const float* normal   = (const float*)d_in[i++];
  const float* DL       = (const float*)d_in[i++];
  const float* pbr_ln_g = (const float*)d_in[i++];
  const float* pbr_ln_b = (const float*)d_in[i++];
  const float* pbr_w1   = (const float*)d_in[i++];
  const float* pbr_b1   = (const float*)d_in[i++];
  const float* pbr_w2   = (const float*)d_in[i++];
  const float* pbr_b2   = (const float*)d_in[i++];
  const float* pbr_w3   = (const float*)d_in[i++];
  const float* pbr_b3   = (const float*)d_in[i++];
  const float* pbr_w4   = (const float*)d_in[i++];
  const float* pbr_b4   = (const float*)d_in[i++];
  const float* tv1_ln_g = (const float*)d_in[i++];
  const float* tv1_ln_b = (const float*)d_in[i++];
  const float* tv1_w    = (const float*)d_in[i++];
  const float* to1_w    = (const float*)d_in[i++];
  const float* to1_b    = (const float*)d_in[i++];
  const float* n1_ln_g  = (const float*)d_in[i++];
  const float* n1_ln_b  = (const float*)d_in[i++];
  const float* n1_w1    = (const float*)d_in[i++];
  const float* n1_b1    = (const float*)d_in[i++];
  const float* n1_w2    = (const float*)d_in[i++];
  const float* n1_b2    = (const float*)d_in[i++];
  const float* tv2_ln_g = (const float*)d_in[i++];
  const float* tv2_ln_b = (const float*)d_in[i++];
  const float* tv2_w    = (const float*)d_in[i++];
  const float* to2_w    = (const float*)d_in[i++];
  const float* to2_b    = (const float*)d_in[i++];
  const float* n2_ln_g  = (const float*)d_in[i++];
  const float* n2_ln_b  = (const float*)d_in[i++];
  const float* n2_w1    = (const float*)d_in[i++];
  const float* n2_b1    = (const float*)d_in[i++];
  const float* n2_w2    = (const float*)d_in[i++];
  const float* n2_b2    = (const float*)d_in[i++];
  const float* brdf_ln_g= (const float*)d_in[i++];
  const float* brdf_ln_b= (const float*)d_in[i++];
  const float* brdf_w1  = (const float*)d_in[i++];
  const float* brdf_b1  = (const float*)d_in[i++];
  const float* brdf_w2  = (const float*)d_in[i++];
  const float* brdf_b2  = (const float*)d_in[i++];

  float* ws = (float*)d_ws;

  mva_phaseA<<<dim3(NBA), dim3(NTA), 0, stream>>>(
      view_dir, normal, DL, pbr_ln_g, pbr_ln_b,
      pbr_w1, pbr_b1, pbr_w2, pbr_b2, pbr_w3, pbr_b3, pbr_w4, pbr_b4, ws);

  mva_phaseB1<<<dim3(NBB1), dim3(NTB), 0, stream>>>(
      rgb, fm, proj_err, ws,
      tv1_ln_g, tv1_ln_b, tv1_w, to1_w, to1_b,
      n1_ln_g, n1_ln_b, n1_w1, n1_b1, n1_w2, n1_b2,
      tv2_ln_g, tv2_ln_b, tv2_w);

  mva_phaseB2<<<dim3(NBB2), dim3(NTB), 0, stream>>>(
      rgb, fm, ws,
      to2_w, to2_b,
      n2_ln_g, n2_ln_b, n2_w1, n2_b1, n2_w2, n2_b2,
      brdf_ln_g, brdf_ln_b, brdf_w1, brdf_b1, brdf_w2, brdf_b2,
      (float*)d_out);
}